// Round 5
// baseline (401.620 us; speedup 1.0000x reference)
//
#include <hip/hip_runtime.h>
#include <math.h>
#include <stdio.h>
#include <stdint.h>

#define GXD 272
#define GYD 112
#define GZD 272
#define NROT 36
#define CCLS (GXD*GZD)     /* 73984 = 289*256 */
#define KSMP 1024          /* NUM_PROPOSAL*OVERSAMPLE */
#define NPROP 256
#define HSLOTS 2048        /* sampled-cell hash table slots */
#define YH 56              /* y-half size */
#define NBINS (GXD*2)      /* 544: (x-slice, y-half) bins */
#define SLICE (GYD*GZD)    /* 30464 cells per x-slice */
#define SVCAP 64           /* survivor capacity per row (E~21) */
#define ROWG 32            /* row groups in prefilter grid (32 rows/thread) */

struct RotTab { float c[NROT]; float s[NROT]; };

__device__ __forceinline__ uint32_t cell_hash(int flat) {
    return ((uint32_t)flat * 2654435761u) >> 21;  // top 11 bits -> 0..2047
}

// rotl via single v_alignbit_b32: alignbit(x,x,s) = rotr(x,s); rotl(x,r)=rotr(x,32-r)
#define ROTL_AB(x, r) __builtin_amdgcn_alignbit((x), (x), 32u - (r))

// ---------------- threefry2x32, key (0,42), counter (0,i), out = o0^o1 ----------------
// JAX partitionable random_bits semantics. Injection x0-adds folded into the next
// round's add (v_add3_u32): exact mod-2^32, ~67 VALU ops/chain.
__device__ __forceinline__ uint32_t tf_bits(uint32_t i) {
    constexpr uint32_t K1  = 42u;
    constexpr uint32_t KS2 = 42u ^ 0x1BD11BDAu;
    uint32_t x0 = 0u, x1 = i + K1;                     // inj0 (k0 == 0)
#define TF_R(r)  { x0 += x1; x1 = ROTL_AB(x1, r); x1 ^= x0; }
#define TF_RI(r, I0, I1) { x1 += (I1); x0 = x0 + (I0) + x1; x1 = ROTL_AB(x1, r); x1 ^= x0; }
    TF_R(13) TF_R(15) TF_R(26) TF_R(6)
    TF_RI(17, K1,  KS2 + 1u)  TF_R(29) TF_R(16) TF_R(24)
    TF_RI(13, KS2, 2u)        TF_R(15) TF_R(26) TF_R(6)
    TF_RI(17, 0u,  K1 + 3u)   TF_R(29) TF_R(16) TF_R(24)
    TF_RI(13, K1,  KS2 + 4u)  TF_R(15) TF_R(26) TF_R(6)
#undef TF_R
#undef TF_RI
    return (x0 + KS2) ^ (x1 + 5u);                     // inj5 folded into output
}

// ---- batched threefry: 8 independent chains in register lockstep ----
// Counters ib, ib+CCLS, ..., ib+7*CCLS. Macro form (NOT inner j-loop per op-group)
// is the variant measured to keep all 16 chain registers live (R3: VGPR_Count=16),
// i.e. the compiler does NOT re-serialize it. Bit-identical per chain to tf_bits.
template<int W>
__device__ __forceinline__ void tf_batch(uint32_t ib, uint32_t* out) {
    constexpr uint32_t K1  = 42u;
    constexpr uint32_t KS2 = 42u ^ 0x1BD11BDAu;
    uint32_t x0[W], x1[W];
#pragma unroll
    for (int j = 0; j < W; ++j) {
        x0[j] = 0u;                                   // x0 += k0 (k0 == 0)
        x1[j] = ib + (uint32_t)(j * CCLS) + K1;       // x1 += k1
    }
#define TFB_ROUND(RR) _Pragma("unroll") \
    for (int j = 0; j < W; ++j) { x0[j] += x1[j]; x1[j] = ROTL_AB(x1[j], RR); x1[j] ^= x0[j]; }
#define TFB_INJ(IA, IB) _Pragma("unroll") \
    for (int j = 0; j < W; ++j) { x0[j] += (IA); x1[j] += (IB); }
    TFB_ROUND(13) TFB_ROUND(15) TFB_ROUND(26) TFB_ROUND(6)  TFB_INJ(K1,  KS2 + 1u)
    TFB_ROUND(17) TFB_ROUND(29) TFB_ROUND(16) TFB_ROUND(24) TFB_INJ(KS2, 2u)
    TFB_ROUND(13) TFB_ROUND(15) TFB_ROUND(26) TFB_ROUND(6)  TFB_INJ(0u,  K1 + 3u)
    TFB_ROUND(17) TFB_ROUND(29) TFB_ROUND(16) TFB_ROUND(24) TFB_INJ(K1,  KS2 + 4u)
    TFB_ROUND(13) TFB_ROUND(15) TFB_ROUND(26) TFB_ROUND(6)  TFB_INJ(KS2, 5u)
#undef TFB_ROUND
#undef TFB_INJ
#pragma unroll
    for (int j = 0; j < W; ++j) out[j] = x0[j] ^ x1[j];
}

__device__ __forceinline__ float uniform_from_bits(uint32_t b) {
    const float TINY = 1.1754943508222875e-38f; // np.finfo(float32).tiny
    float f = __uint_as_float((b >> 9) | 0x3f800000u) - 1.0f;
    float u = __fadd_rn(__fmul_rn(f, 1.0f), TINY);
    return fmaxf(TINY, u);
}

// gumbel = -log(-log(u)); f32 logs via double rounding (== correctly-rounded logf)
__device__ __forceinline__ float gumbel_from_u(float u) {
    float l1 = (float)log((double)u);
    float l2 = (float)log((double)(-l1));
    return -l2;
}

// ---- vote voxel helpers: MUST stay bit-identical across all passes ----
__device__ __forceinline__ bool vote_iy(float py, float oy, float c0y, int& iy) {
    float ty = __fadd_rn(py, oy);
    float vy = __fadd_rn(__fdiv_rn(__fsub_rn(ty, c0y), 0.03f), 0.5f);
    iy = (int)floorf(vy);
    return (iy >= 0 && iy < GYD);
}
__device__ __forceinline__ bool vote_xz(float px, float pz, float ox, float oz,
                                        float c, float s, float c0x, float c0z,
                                        int& ix, int& iz) {
    float rx = __fadd_rn(__fmul_rn(ox, c), __fmul_rn(oz, s));
    float rz = __fadd_rn(__fmul_rn(-ox, s), __fmul_rn(oz, c));
    float tx = __fadd_rn(px, rx);
    float tz = __fadd_rn(pz, rz);
    float vx = __fadd_rn(__fdiv_rn(__fsub_rn(tx, c0x), 0.03f), 0.5f);
    float vz = __fadd_rn(__fdiv_rn(__fsub_rn(tz, c0z), 0.03f), 0.5f);
    ix = (int)floorf(vx);
    iz = (int)floorf(vz);
    return (ix >= 0 && ix < GXD && iz >= 0 && iz < GZD);
}

// ---------------- K1a: count votes per (x-slice, y-half) bin ----------------
__global__ __launch_bounds__(256) void k_count(const float* __restrict__ pc, const float* __restrict__ xyz,
                          const float* __restrict__ corners, int N, RotTab rt,
                          int* __restrict__ bincnt) {
    __shared__ int h[NBINS];
    int tid = threadIdx.x;
    for (int j = tid; j < NBINS; j += 256) h[j] = 0;
    __syncthreads();
    int i = blockIdx.x * 256 + tid;
    if (i < N) {
        float px = pc[3*i], py = pc[3*i+1], pz = pc[3*i+2];
        float ox = xyz[3*i], oy = xyz[3*i+1], oz = xyz[3*i+2];
        int iy;
        if (vote_iy(py, oy, corners[1], iy)) {
            int ybit = (iy >= YH) ? 1 : 0;
            float c0x = corners[0], c0z = corners[2];
            for (int r = 0; r < NROT; ++r) {
                int ix, iz;
                if (vote_xz(px, pz, ox, oz, rt.c[r], rt.s[r], c0x, c0z, ix, iz))
                    atomicAdd(&h[ix*2 + ybit], 1);
            }
        }
    }
    __syncthreads();
    for (int j = tid; j < NBINS; j += 256) if (h[j]) atomicAdd(&bincnt[j], h[j]);
}

// ---------------- K1b: parallel exclusive scan over 544 bins ----------------
__global__ __launch_bounds__(576) void k_prefix(const int* __restrict__ bincnt,
                         int* __restrict__ binbase, int* __restrict__ bincur) {
    __shared__ int sc[576];
    int tid = threadIdx.x;
    int v = (tid < NBINS) ? bincnt[tid] : 0;
    sc[tid] = v;
    __syncthreads();
    for (int off = 1; off < 576; off <<= 1) {
        int x = sc[tid];
        if (tid >= off) x += sc[tid - off];
        __syncthreads();
        sc[tid] = x;
        __syncthreads();
    }
    if (tid < NBINS) {
        int excl = sc[tid] - v;
        binbase[tid] = excl;
        bincur[tid] = excl;
    }
}

// ---------------- K1c: write vote records binned (uint2: flat, w-bits) ----------------
__global__ __launch_bounds__(256) void k_binwrite(const float* __restrict__ pc, const float* __restrict__ xyz,
                          const float* __restrict__ prob, const float* __restrict__ corners,
                          int N, RotTab rt, int* __restrict__ bincur,
                          uint2* __restrict__ vrec) {
    __shared__ int h[NBINS];
    __shared__ int bbase[NBINS];
    int tid = threadIdx.x;
    for (int j = tid; j < NBINS; j += 256) h[j] = 0;
    __syncthreads();
    int i = blockIdx.x * 256 + tid;
    float px=0, py=0, pz=0, ox=0, oy=0, oz=0, w0=0, c0x=0, c0z=0;
    int iy = -1, ybit = 0;
    bool act = false;
    if (i < N) {
        px = pc[3*i]; py = pc[3*i+1]; pz = pc[3*i+2];
        ox = xyz[3*i]; oy = xyz[3*i+1]; oz = xyz[3*i+2];
        w0 = prob[i];
        c0x = corners[0]; c0z = corners[2];
        if (vote_iy(py, oy, corners[1], iy)) {
            act = true;
            ybit = (iy >= YH) ? 1 : 0;
        }
    }
    if (act) {
        for (int r = 0; r < NROT; ++r) {
            int ix, iz;
            if (vote_xz(px, pz, ox, oz, rt.c[r], rt.s[r], c0x, c0z, ix, iz))
                atomicAdd(&h[ix*2 + ybit], 1);
        }
    }
    __syncthreads();
    for (int j = tid; j < NBINS; j += 256) {
        int cnt = h[j];
        bbase[j] = cnt ? atomicAdd(&bincur[j], cnt) : 0;
        h[j] = 0;  // reuse as local cursor
    }
    __syncthreads();
    if (act) {
        for (int r = 0; r < NROT; ++r) {
            int ix, iz;
            if (vote_xz(px, pz, ox, oz, rt.c[r], rt.s[r], c0x, c0z, ix, iz)) {
                int bin = ix*2 + ybit;
                int rank = atomicAdd(&h[bin], 1);
                int slot = bbase[bin] + rank;
                vrec[slot] = make_uint2((uint32_t)((ix*GYD + iy)*GZD + iz), __float_as_uint(w0));
            }
        }
    }
}

// ---------------- K1d: per-bin LDS accumulate -> gobj + fused per-column half-max ----------------
__global__ __launch_bounds__(256) void k_accum(const int* __restrict__ binbase,
                          const int* __restrict__ bincnt,
                          const uint2* __restrict__ vrec,
                          float* __restrict__ gobj,
                          float* __restrict__ cmax, int* __restrict__ camax) {
    __shared__ float tile[YH*GZD];   // 56*272*4 = 60928 B
    int b = blockIdx.x;
    int x = b >> 1, yh = b & 1;
    int tid = threadIdx.x;
    for (int j = tid; j < YH*GZD; j += 256) tile[j] = 0.0f;
    __syncthreads();
    int lo = binbase[b], n = bincnt[b];
    int xoff = x * SLICE;
    int yoff = yh * (YH*GZD);
    int sub = xoff + yoff;
    for (int j = lo + tid; j < lo + n; j += 256) {
        uint2 rec = vrec[j];
        atomicAdd(&tile[(int)rec.x - sub], __uint_as_float(rec.y));
    }
    __syncthreads();
    float* dst = gobj + (size_t)sub;
    for (int j = tid; j < YH*GZD; j += 256) dst[j] = tile[j];
    // per-z column max/argmax over this half-slab (strict > => first occurrence)
    for (int z = tid; z < GZD; z += 256) {
        float m = tile[z];
        int mi = 0;
        for (int y = 1; y < YH; ++y) {
            float v = tile[y*GZD + z];
            if (v > m) { m = v; mi = y; }
        }
        cmax[b*GZD + z] = m;
        camax[b*GZD + z] = mi;
    }
}

// ---------------- K2: combine y-halves -> logits/yidx; sum(dist) ----------------
__global__ __launch_bounds__(256) void k_colmax2(const float* __restrict__ cmax,
                         const int* __restrict__ camax,
                         float* __restrict__ logits, int* __restrict__ yidx,
                         float* __restrict__ sumdist) {
    int c = blockIdx.x * blockDim.x + threadIdx.x;
    float d = 0.0f;
    if (c < CCLS) {
        int x = c / GZD, z = c % GZD;
        int b0 = (x*2)*GZD + z;
        int b1 = b0 + GZD;
        float m0 = cmax[b0], m1 = cmax[b1];
        float m; int mi;
        if (m1 > m0) { m = m1; mi = YH + camax[b1]; }   // strict >: ties keep lower half
        else         { m = m0; mi = camax[b0]; }
        d = __fsqrt_rn(__fadd_rn(m, 1e-7f));
        yidx[c] = mi;
        logits[c] = (float)log((double)__fadd_rn(d, 1e-30f));
    }
    __shared__ float sred[256];
    int tid = threadIdx.x;
    sred[tid] = d; __syncthreads();
    for (int off = 128; off > 0; off >>= 1) {
        if (tid < off) sred[tid] += sred[tid+off];
        __syncthreads();
    }
    if (tid == 0) atomicAdd(sumdist, sred[0]);
}

// ---------------- K2b: per-column integer bits-threshold ----------------
// survivor v = gumbel(u)+L > B0  <=>  u > u* = exp(-exp(L-B0)).  u = (bits>>9)*2^-23
// (monotone in bits).  Store bth = (floor(u*·2^23)-2)<<9: test (bits >= bth) can
// only OVER-include vs the exact condition (margin 2 mantissa steps + 0.05 in B0).
__global__ __launch_bounds__(256) void k_thresh(const float* __restrict__ logits,
                                                const float* __restrict__ sumdist,
                                                uint32_t* __restrict__ bth) {
    int c = blockIdx.x * blockDim.x + threadIdx.x;
    if (c >= CCLS) return;
    double B0 = log((double)*sumdist) - 3.0;
    double t = exp(-exp((double)logits[c] - (B0 - 0.05)));
    long long k_th = (long long)floor(t * 8388608.0) - 2;
    uint32_t b;
    if (k_th <= 0)              b = 0u;           // everything survives
    else if (k_th >= 8388608LL) b = 0xFFFFFFFFu;  // ~nothing survives (over-include, harmless)
    else                        b = (uint32_t)k_th << 9;
    bth[c] = b;
}

// ---------------- K3: prefilter — full grid + verified 8-chain register ILP ----------------
// Grid (289, 32) as R4 (measured-best packing); rows processed in 4 batches of 8
// lockstep chains (tf_batch, VGPR-verified interleave). Single-variable ILP test.
__global__ __launch_bounds__(256) void k_prefilter(const uint32_t* __restrict__ bth,
                                                   int* __restrict__ svcnt,
                                                   uint2* __restrict__ svrec) {
    int c = blockIdx.x * 256 + threadIdx.x;   // 289*256 == CCLS exactly
    int k0 = blockIdx.y * (KSMP / ROWG);
    uint32_t th = bth[c];
    uint32_t i = (uint32_t)k0 * (uint32_t)CCLS + (uint32_t)c;
#pragma unroll 1
    for (int kk = 0; kk < KSMP / ROWG; kk += 8) {
        uint32_t b[8];
        tf_batch<8>(i, b);
#pragma unroll
        for (int j = 0; j < 8; ++j) {
            if (__builtin_expect(b[j] >= th, 0)) {
                int row = k0 + kk + j;
                int idx = atomicAdd(&svcnt[row], 1);
                if (idx < SVCAP) svrec[row * SVCAP + idx] = make_uint2((uint32_t)c, b[j]);
            }
        }
        i += 8u * (uint32_t)CCLS;
    }
}

// ---------------- K3f: per-row exact eval + argmax (1 wave/row) ----------------
__global__ __launch_bounds__(64) void k_finalize(const float* __restrict__ logits,
                                                 const int* __restrict__ svcnt,
                                                 const uint2* __restrict__ svrec,
                                                 int* __restrict__ samples) {
    int k = blockIdx.x;
    int tid = threadIdx.x;   // 64 threads = 1 wave
    int n = svcnt[k];
    float best = -INFINITY; int bc = 0x7fffffff;
    if (n > 0 && n <= SVCAP) {
        if (tid < n) {
            uint2 rec = svrec[k * SVCAP + tid];
            int c = (int)rec.x;
            best = __fadd_rn(gumbel_from_u(uniform_from_bits(rec.y)), logits[c]);
            bc = c;
        }
    } else {
        // empty (P ~ e^-21) or overflow (Poisson(21) tail @64): exact full scan
        uint32_t base = (uint32_t)k * (uint32_t)CCLS;
        for (int c = tid; c < CCLS; c += 64) {
            float v = __fadd_rn(gumbel_from_u(uniform_from_bits(tf_bits(base + (uint32_t)c))), logits[c]);
            if (v > best || (v == best && c < bc)) { best = v; bc = c; }
        }
    }
    // wave butterfly reduce on (max, min-index) — order-independent predicate
    for (int off = 32; off > 0; off >>= 1) {
        float v2 = __shfl_down(best, off);
        int   i2 = __shfl_down(bc, off);
        if (v2 > best || (v2 == best && i2 < bc)) { best = v2; bc = i2; }
    }
    if (tid == 0) samples[k] = bc;
}

// ---------------- K3b: build sampled-cell hash table (single block) ----------------
__global__ __launch_bounds__(256) void k_build_table(const int* __restrict__ samples,
                                                     const int* __restrict__ yidx,
                                                     int* __restrict__ hkeys,
                                                     float* __restrict__ gsmall) {
    int tid = threadIdx.x;
    for (int j = tid; j < HSLOTS; j += 256) hkeys[j] = -1;
    for (int j = tid; j < 3*HSLOTS; j += 256) gsmall[j] = 0.0f;
    __syncthreads();
    for (int k = tid; k < KSMP; k += 256) {
        int s = samples[k];
        int xi = s / GZD, zi = s % GZD;
        int yi = yidx[s];
        int flat = (xi*GYD + yi)*GZD + zi;
        uint32_t h = cell_hash(flat);
        for (;;) {
            int prev = atomicCAS(&hkeys[h], -1, flat);
            if (prev == -1 || prev == flat) break;
            h = (h + 1) & (HSLOTS - 1);
        }
    }
}

// ---------------- K3c: replay votes (all 36 rots per thread), accumulate scale sums ----------------
__global__ __launch_bounds__(256) void k_scale_scatter(const float* __restrict__ pc, const float* __restrict__ xyz,
                          const float* __restrict__ scale, const float* __restrict__ prob,
                          const float* __restrict__ corners,
                          const int* __restrict__ hkeys, float* __restrict__ gsmall,
                          int N, RotTab rt) {
    __shared__ int lk[HSLOTS];
    for (int j = threadIdx.x; j < HSLOTS; j += 256) lk[j] = hkeys[j];
    __syncthreads();
    int i = blockIdx.x * 256 + threadIdx.x;
    if (i >= N) return;
    float px = pc[3*i], py = pc[3*i+1], pz = pc[3*i+2];
    float ox = xyz[3*i], oy = xyz[3*i+1], oz = xyz[3*i+2];
    int iy;
    if (!vote_iy(py, oy, corners[1], iy)) return;
    float c0x = corners[0], c0z = corners[2];
    int iyo = iy * GZD;
    float w0 = prob[i];
    float ws0 = __fmul_rn(w0, scale[3*i]);
    float ws1 = __fmul_rn(w0, scale[3*i+1]);
    float ws2 = __fmul_rn(w0, scale[3*i+2]);
    for (int r = 0; r < NROT; ++r) {
        int ix, iz;
        if (!vote_xz(px, pz, ox, oz, rt.c[r], rt.s[r], c0x, c0z, ix, iz)) continue;
        int flat = ix * SLICE + iyo + iz;
        uint32_t h = cell_hash(flat);
        int slot = -1;
        for (;;) {
            int key = lk[h];
            if (key == flat) { slot = (int)h; break; }
            if (key == -1) break;
            h = (h + 1) & (HSLOTS - 1);
        }
        if (slot < 0) continue;
        atomicAdd(&gsmall[3*slot+0], ws0);
        atomicAdd(&gsmall[3*slot+1], ws1);
        atomicAdd(&gsmall[3*slot+2], ws2);
    }
}

// ---------------- K4: one block per sample — world loc, scale, keep ----------------
__global__ __launch_bounds__(256) void k_post(const float* __restrict__ gobj,
                       const int* __restrict__ hkeys, const float* __restrict__ gsmall,
                       const int* __restrict__ yidx, const int* __restrict__ samples,
                       const float* __restrict__ corners, const float* __restrict__ vp, int M,
                       float* __restrict__ world, float* __restrict__ scv, int* __restrict__ keep) {
    int k = blockIdx.x;
    int tid = threadIdx.x;
    int s = samples[k];
    int xi = s / GZD, zi = s % GZD;
    int yi = yidx[s];
    float wx = __fadd_rn(__fmul_rn((float)xi, 0.03f), corners[0]);
    float wy = __fadd_rn(__fmul_rn((float)yi, 0.03f), corners[1]);
    float wz = __fadd_rn(__fmul_rn((float)zi, 0.03f), corners[2]);

    float dmin = INFINITY;
    for (int j = tid; j < M; j += 256) {
        float dx = __fsub_rn(wx, vp[3*j]);
        float dy = __fsub_rn(wy, vp[3*j+1]);
        float dz = __fsub_rn(wz, vp[3*j+2]);
        float sq = __fadd_rn(__fadd_rn(__fmul_rn(dx,dx), __fmul_rn(dy,dy)), __fmul_rn(dz,dz));
        dmin = fminf(dmin, __fsqrt_rn(sq));
    }
    __shared__ float sm[256];
    sm[tid] = dmin; __syncthreads();
    for (int off = 128; off > 0; off >>= 1) {
        if (tid < off) sm[tid] = fminf(sm[tid], sm[tid+off]);
        __syncthreads();
    }
    if (tid == 0) {
        world[3*k] = wx; world[3*k+1] = wy; world[3*k+2] = wz;
        int flat = (xi*GYD + yi)*GZD + zi;
        uint32_t h = cell_hash(flat);
        while (hkeys[h] != flat) h = (h + 1) & (HSLOTS - 1);  // guaranteed present
        float go = __fadd_rn(gobj[flat], 1e-7f);
        scv[3*k+0] = __fdiv_rn(gsmall[3*h+0], go);
        scv[3*k+1] = __fdiv_rn(gsmall[3*h+1], go);
        scv[3*k+2] = __fdiv_rn(gsmall[3*h+2], go);
        keep[k] = (sm[0] < 0.3f) ? 1 : 0;
    }
}

// ---------------- K5: stable 0/1 selection via parallel prefix-sum ----------------
__global__ __launch_bounds__(256) void k_select(const float* __restrict__ world,
                                                const float* __restrict__ scv,
                                                const int* __restrict__ keep,
                                                float* __restrict__ out) {
    __shared__ int kp[KSMP];
    __shared__ int tsum[256];
    __shared__ int sel[NPROP];
    __shared__ int anyk;
    int tid = threadIdx.x;
    if (tid == 0) anyk = 0;
    __syncthreads();
    int a = 0;
    for (int j = tid; j < KSMP; j += 256) { int v = keep[j]; kp[j] = v; a |= v; }
    if (a) anyk = 1;           // benign race, all writers store 1
    __syncthreads();
    int any = anyk;
    int j0 = tid * 4;
    int k0v = any ? kp[j0]   : 1;
    int k1v = any ? kp[j0+1] : 1;
    int k2v = any ? kp[j0+2] : 1;
    int k3v = any ? kp[j0+3] : 1;
    int s0 = k0v, s1 = s0 + k1v, s2 = s1 + k2v, s3 = s2 + k3v;
    tsum[tid] = s3;
    __syncthreads();
    for (int off = 1; off < 256; off <<= 1) {
        int x = tsum[tid];
        if (tid >= off) x += tsum[tid - off];
        __syncthreads();
        tsum[tid] = x;
        __syncthreads();
    }
    int base = (tid > 0) ? tsum[tid-1] : 0;
    int nk = tsum[255];  // total kept
    int inc[4] = { base + s0, base + s1, base + s2, base + s3 };
    int kv[4]  = { k0v, k1v, k2v, k3v };
    for (int q = 0; q < 4; ++q) {
        int j = j0 + q;
        int slot = kv[q] ? (inc[q] - 1) : (nk + j - inc[q]);
        if (slot < NPROP) sel[slot] = j;
    }
    __syncthreads();
    if (tid < NPROP) {
        int sidx = sel[tid];
        out[3*tid+0] = world[3*sidx+0];
        out[3*tid+1] = world[3*sidx+1];
        out[3*tid+2] = world[3*sidx+2];
        out[3*NPROP + tid] = 0.0f;                 // probs
        out[4*NPROP + 3*tid + 0] = scv[3*sidx+0];
        out[4*NPROP + 3*tid + 1] = scv[3*sidx+1];
        out[4*NPROP + 3*tid + 2] = scv[3*sidx+2];
    }
}

extern "C" void kernel_launch(void* const* d_in, const int* in_sizes, int n_in,
                              void* d_out, int out_size, void* d_ws, size_t ws_size,
                              hipStream_t stream) {
    const float* pc      = (const float*)d_in[0];
    const float* xyz     = (const float*)d_in[1];
    const float* scale   = (const float*)d_in[2];
    const float* prob    = (const float*)d_in[3];
    const float* corners = (const float*)d_in[4];
    const float* vp      = (const float*)d_in[5];
    int N = in_sizes[0] / 3;
    int M = in_sizes[5] / 3;
    int NV = N * NROT;

    const size_t G = (size_t)GXD * GYD * GZD;  // 8,286,208
    float* gobj    = (float*)d_ws;
    float* sumdist = gobj + G;              // 1 float   — zeroed below
    int*   bincnt  = (int*)(sumdist + 1);   // NBINS     — zeroed below
    int*   svcnt   = bincnt + NBINS;        // KSMP      — zeroed below
    int*   binbase = svcnt + KSMP;
    int*   bincur  = binbase + NBINS;
    float* logits  = (float*)(bincur + NBINS);
    uint32_t* bth  = (uint32_t*)(logits + CCLS);
    int*   yidx    = (int*)(bth + CCLS);
    int*   samples = yidx + CCLS;
    int*   hkeys   = samples + KSMP;
    float* gsmall  = (float*)(hkeys + HSLOTS);
    float* world   = gsmall + 3*HSLOTS;
    float* scv     = world + 3*KSMP;
    int*   keep    = (int*)(scv + 3*KSMP);
    float* cmax    = (float*)(keep + KSMP);        // NBINS*GZD
    int*   camax   = (int*)(cmax + (size_t)NBINS*GZD);
    uint2* svrec   = (uint2*)(((uintptr_t)(camax + (size_t)NBINS*GZD) + 15) & ~(uintptr_t)15);
    uint2* vrec    = svrec + (size_t)KSMP * SVCAP;
    size_t need = (size_t)((char*)(vrec + NV) - (char*)d_ws);
    if (ws_size < need) {
        fprintf(stderr, "kernel_launch: ws_size %zu < needed %zu\n", ws_size, need);
        return;
    }

    // zero sumdist + bincnt + svcnt (contiguous; gobj fully written by k_accum)
    hipMemsetAsync(sumdist, 0, (1 + NBINS + KSMP)*sizeof(int), stream);

    // rotation table: f32 theta chain exactly as reference, cos/sin in double -> f32
    RotTab rt;
    const float twopi = (float)(2.0 * M_PI);
    for (int r = 0; r < NROT; ++r) {
        float th = (twopi * (float)r) / 36.0f;
        rt.c[r] = (float)cos((double)th);
        rt.s[r] = (float)sin((double)th);
    }

    int pblocks = (N + 255) / 256;
    k_count<<<pblocks, 256, 0, stream>>>(pc, xyz, corners, N, rt, bincnt);
    k_prefix<<<1, 576, 0, stream>>>(bincnt, binbase, bincur);
    k_binwrite<<<pblocks, 256, 0, stream>>>(pc, xyz, prob, corners, N, rt, bincur, vrec);
    k_accum<<<NBINS, 256, 0, stream>>>(binbase, bincnt, vrec, gobj, cmax, camax);
    k_colmax2<<<CCLS / 256, 256, 0, stream>>>(cmax, camax, logits, yidx, sumdist);
    k_thresh<<<CCLS / 256, 256, 0, stream>>>(logits, sumdist, bth);
    dim3 pf_grid(CCLS / 256, ROWG);
    k_prefilter<<<pf_grid, 256, 0, stream>>>(bth, svcnt, svrec);
    k_finalize<<<KSMP, 64, 0, stream>>>(logits, svcnt, svrec, samples);
    k_build_table<<<1, 256, 0, stream>>>(samples, yidx, hkeys, gsmall);
    k_scale_scatter<<<pblocks, 256, 0, stream>>>(pc, xyz, scale, prob, corners, hkeys, gsmall, N, rt);
    k_post<<<KSMP, 256, 0, stream>>>(gobj, hkeys, gsmall, yidx, samples, corners, vp, M, world, scv, keep);
    k_select<<<1, 256, 0, stream>>>(world, scv, keep, (float*)d_out);
}

// Round 6
// 393.542 us; speedup vs baseline: 1.0205x; 1.0205x over previous
//
#include <hip/hip_runtime.h>
#include <math.h>
#include <stdio.h>
#include <stdint.h>

#define GXD 272
#define GYD 112
#define GZD 272
#define NROT 36
#define CCLS (GXD*GZD)     /* 73984 = 289*256 */
#define KSMP 1024          /* NUM_PROPOSAL*OVERSAMPLE */
#define NPROP 256
#define HSLOTS 2048        /* sampled-cell hash table slots */
#define YH 56              /* y-half size */
#define NBINS (GXD*2)      /* 544: (x-slice, y-half) bins */
#define SLICE (GYD*GZD)    /* 30464 cells per x-slice */
#define SVCAP 64           /* survivor capacity per row (E~21) */
#define ROWG 32            /* row groups in prefilter grid (32 rows/thread) */

struct RotTab { float c[NROT]; float s[NROT]; };

__device__ __forceinline__ uint32_t cell_hash(int flat) {
    return ((uint32_t)flat * 2654435761u) >> 21;  // top 11 bits -> 0..2047
}

// rotl via single v_alignbit_b32: alignbit(x,x,s) = rotr(x,s); rotl(x,r)=rotr(x,32-r)
#define ROTL_AB(x, r) __builtin_amdgcn_alignbit((x), (x), 32u - (r))

// ---------------- threefry2x32, key (0,42), counter (0,i), out = o0^o1 ----------------
// JAX partitionable random_bits semantics. Injection x0-adds folded into the next
// round's add (v_add3_u32): exact mod-2^32, ~67 VALU ops/chain. (R4 serial form:
// measured-best; interleave attempts R0/R5 were re-serialized by the compiler,
// and instruction-count A/Bs (R3) showed time is insensitive to op count.)
__device__ __forceinline__ uint32_t tf_bits(uint32_t i) {
    constexpr uint32_t K1  = 42u;
    constexpr uint32_t KS2 = 42u ^ 0x1BD11BDAu;
    uint32_t x0 = 0u, x1 = i + K1;                     // inj0 (k0 == 0)
#define TF_R(r)  { x0 += x1; x1 = ROTL_AB(x1, r); x1 ^= x0; }
#define TF_RI(r, I0, I1) { x1 += (I1); x0 = x0 + (I0) + x1; x1 = ROTL_AB(x1, r); x1 ^= x0; }
    TF_R(13) TF_R(15) TF_R(26) TF_R(6)
    TF_RI(17, K1,  KS2 + 1u)  TF_R(29) TF_R(16) TF_R(24)
    TF_RI(13, KS2, 2u)        TF_R(15) TF_R(26) TF_R(6)
    TF_RI(17, 0u,  K1 + 3u)   TF_R(29) TF_R(16) TF_R(24)
    TF_RI(13, K1,  KS2 + 4u)  TF_R(15) TF_R(26) TF_R(6)
#undef TF_R
#undef TF_RI
    return (x0 + KS2) ^ (x1 + 5u);                     // inj5 folded into output
}

__device__ __forceinline__ float uniform_from_bits(uint32_t b) {
    const float TINY = 1.1754943508222875e-38f; // np.finfo(float32).tiny
    float f = __uint_as_float((b >> 9) | 0x3f800000u) - 1.0f;
    float u = __fadd_rn(__fmul_rn(f, 1.0f), TINY);
    return fmaxf(TINY, u);
}

// gumbel = -log(-log(u)); f32 logs via double rounding (== correctly-rounded logf)
__device__ __forceinline__ float gumbel_from_u(float u) {
    float l1 = (float)log((double)u);
    float l2 = (float)log((double)(-l1));
    return -l2;
}

// ---- vote voxel helpers: MUST stay bit-identical across all passes ----
__device__ __forceinline__ bool vote_iy(float py, float oy, float c0y, int& iy) {
    float ty = __fadd_rn(py, oy);
    float vy = __fadd_rn(__fdiv_rn(__fsub_rn(ty, c0y), 0.03f), 0.5f);
    iy = (int)floorf(vy);
    return (iy >= 0 && iy < GYD);
}
__device__ __forceinline__ bool vote_xz(float px, float pz, float ox, float oz,
                                        float c, float s, float c0x, float c0z,
                                        int& ix, int& iz) {
    float rx = __fadd_rn(__fmul_rn(ox, c), __fmul_rn(oz, s));
    float rz = __fadd_rn(__fmul_rn(-ox, s), __fmul_rn(oz, c));
    float tx = __fadd_rn(px, rx);
    float tz = __fadd_rn(pz, rz);
    float vx = __fadd_rn(__fdiv_rn(__fsub_rn(tx, c0x), 0.03f), 0.5f);
    float vz = __fadd_rn(__fdiv_rn(__fsub_rn(tz, c0z), 0.03f), 0.5f);
    ix = (int)floorf(vx);
    iz = (int)floorf(vz);
    return (ix >= 0 && ix < GXD && iz >= 0 && iz < GZD);
}

// ---------------- K1a: count votes per (x-slice, y-half) bin + cache per-block hist ----------------
__global__ __launch_bounds__(256) void k_count(const float* __restrict__ pc, const float* __restrict__ xyz,
                          const float* __restrict__ corners, int N, RotTab rt,
                          int* __restrict__ bincnt, int* __restrict__ hblk) {
    __shared__ int h[NBINS];
    int tid = threadIdx.x;
    for (int j = tid; j < NBINS; j += 256) h[j] = 0;
    __syncthreads();
    int i = blockIdx.x * 256 + tid;
    if (i < N) {
        float px = pc[3*i], py = pc[3*i+1], pz = pc[3*i+2];
        float ox = xyz[3*i], oy = xyz[3*i+1], oz = xyz[3*i+2];
        int iy;
        if (vote_iy(py, oy, corners[1], iy)) {
            int ybit = (iy >= YH) ? 1 : 0;
            float c0x = corners[0], c0z = corners[2];
            for (int r = 0; r < NROT; ++r) {
                int ix, iz;
                if (vote_xz(px, pz, ox, oz, rt.c[r], rt.s[r], c0x, c0z, ix, iz))
                    atomicAdd(&h[ix*2 + ybit], 1);
            }
        }
    }
    __syncthreads();
    int* hb = hblk + (size_t)blockIdx.x * NBINS;
    for (int j = tid; j < NBINS; j += 256) {
        int cnt = h[j];
        hb[j] = cnt;
        if (cnt) atomicAdd(&bincnt[j], cnt);
    }
}

// ---------------- K1b: parallel exclusive scan over 544 bins ----------------
__global__ __launch_bounds__(576) void k_prefix(const int* __restrict__ bincnt,
                         int* __restrict__ binbase, int* __restrict__ bincur) {
    __shared__ int sc[576];
    int tid = threadIdx.x;
    int v = (tid < NBINS) ? bincnt[tid] : 0;
    sc[tid] = v;
    __syncthreads();
    for (int off = 1; off < 576; off <<= 1) {
        int x = sc[tid];
        if (tid >= off) x += sc[tid - off];
        __syncthreads();
        sc[tid] = x;
        __syncthreads();
    }
    if (tid < NBINS) {
        int excl = sc[tid] - v;
        binbase[tid] = excl;
        bincur[tid] = excl;
    }
}

// ---------------- K1c: write vote records binned (uint2: flat, w-bits) ----------------
// Per-block counts come from hblk (k_count's cache) — no first histogram pass.
__global__ __launch_bounds__(256) void k_binwrite(const float* __restrict__ pc, const float* __restrict__ xyz,
                          const float* __restrict__ prob, const float* __restrict__ corners,
                          int N, RotTab rt, int* __restrict__ bincur,
                          const int* __restrict__ hblk, uint2* __restrict__ vrec) {
    __shared__ int h[NBINS];      // local rank cursor
    __shared__ int bbase[NBINS];  // this block's base per bin
    int tid = threadIdx.x;
    const int* hb = hblk + (size_t)blockIdx.x * NBINS;
    for (int j = tid; j < NBINS; j += 256) {
        int cnt = hb[j];
        bbase[j] = cnt ? atomicAdd(&bincur[j], cnt) : 0;
        h[j] = 0;
    }
    __syncthreads();
    int i = blockIdx.x * 256 + tid;
    if (i < N) {
        float px = pc[3*i], py = pc[3*i+1], pz = pc[3*i+2];
        float ox = xyz[3*i], oy = xyz[3*i+1], oz = xyz[3*i+2];
        int iy;
        if (vote_iy(py, oy, corners[1], iy)) {
            int ybit = (iy >= YH) ? 1 : 0;
            float c0x = corners[0], c0z = corners[2];
            float w0 = prob[i];
            for (int r = 0; r < NROT; ++r) {
                int ix, iz;
                if (vote_xz(px, pz, ox, oz, rt.c[r], rt.s[r], c0x, c0z, ix, iz)) {
                    int bin = ix*2 + ybit;
                    int rank = atomicAdd(&h[bin], 1);
                    int slot = bbase[bin] + rank;
                    vrec[slot] = make_uint2((uint32_t)((ix*GYD + iy)*GZD + iz), __float_as_uint(w0));
                }
            }
        }
    }
}

// ---------------- K1d: per-bin LDS accumulate -> gobj + packed column-max atomicMax ----------------
// packed[c] key = (f32bits(m) << 32) | (0x7F - y_global): max by m; ties -> smaller y
// (exactly first-occurrence over full y, since within-half strict > keeps smallest y).
__global__ __launch_bounds__(256) void k_accum(const int* __restrict__ binbase,
                          const int* __restrict__ bincnt,
                          const uint2* __restrict__ vrec,
                          float* __restrict__ gobj,
                          unsigned long long* __restrict__ packed) {
    __shared__ float tile[YH*GZD];   // 56*272*4 = 60928 B
    int b = blockIdx.x;
    int x = b >> 1, yh = b & 1;
    int tid = threadIdx.x;
    for (int j = tid; j < YH*GZD; j += 256) tile[j] = 0.0f;
    __syncthreads();
    int lo = binbase[b], n = bincnt[b];
    int xoff = x * SLICE;
    int yoff = yh * (YH*GZD);
    int sub = xoff + yoff;
    for (int j = lo + tid; j < lo + n; j += 256) {
        uint2 rec = vrec[j];
        atomicAdd(&tile[(int)rec.x - sub], __uint_as_float(rec.y));
    }
    __syncthreads();
    float* dst = gobj + (size_t)sub;
    for (int j = tid; j < YH*GZD; j += 256) dst[j] = tile[j];
    // per-z column max/argmax over this half-slab (strict > => first occurrence)
    int ybase = yh * YH;
    for (int z = tid; z < GZD; z += 256) {
        float m = tile[z];
        int mi = 0;
        for (int y = 1; y < YH; ++y) {
            float v = tile[y*GZD + z];
            if (v > m) { m = v; mi = y; }
        }
        unsigned long long key = ((unsigned long long)__float_as_uint(m) << 32)
                               | (unsigned long long)(uint32_t)(0x7F - (ybase + mi));
        atomicMax(&packed[x*GZD + z], key);
    }
}

// ---------------- K2: decode packed -> logits/yidx; sum(dist) ----------------
__global__ __launch_bounds__(256) void k_colmax2(const unsigned long long* __restrict__ packed,
                         float* __restrict__ logits, int* __restrict__ yidx,
                         float* __restrict__ sumdist) {
    int c = blockIdx.x * blockDim.x + threadIdx.x;
    unsigned long long key = packed[c];
    float m = __uint_as_float((uint32_t)(key >> 32));
    int mi = 0x7F - (int)(uint32_t)(key & 0xFFFFFFFFu);
    float d = __fsqrt_rn(__fadd_rn(m, 1e-7f));
    yidx[c] = mi;
    logits[c] = (float)log((double)__fadd_rn(d, 1e-30f));
    __shared__ float sred[256];
    int tid = threadIdx.x;
    sred[tid] = d; __syncthreads();
    for (int off = 128; off > 0; off >>= 1) {
        if (tid < off) sred[tid] += sred[tid+off];
        __syncthreads();
    }
    if (tid == 0) atomicAdd(sumdist, sred[0]);
}

// ---------------- K2b: per-column integer bits-threshold ----------------
// survivor v = gumbel(u)+L > B0  <=>  u > u* = exp(-exp(L-B0)).  u = (bits>>9)*2^-23
// (monotone in bits).  Store bth = (floor(u*·2^23)-2)<<9: test (bits >= bth) can
// only OVER-include vs the exact condition (margin 2 mantissa steps + 0.05 in B0).
__global__ __launch_bounds__(256) void k_thresh(const float* __restrict__ logits,
                                                const float* __restrict__ sumdist,
                                                uint32_t* __restrict__ bth) {
    int c = blockIdx.x * blockDim.x + threadIdx.x;
    if (c >= CCLS) return;
    double B0 = log((double)*sumdist) - 3.0;
    double t = exp(-exp((double)logits[c] - (B0 - 0.05)));
    long long k_th = (long long)floor(t * 8388608.0) - 2;
    uint32_t b;
    if (k_th <= 0)              b = 0u;           // everything survives
    else if (k_th >= 8388608LL) b = 0xFFFFFFFFu;  // ~nothing survives (over-include, harmless)
    else                        b = (uint32_t)k_th << 9;
    bth[c] = b;
}

// ---------------- K3: prefilter — one thread per column, 32 rows serial ----------------
// Closed at ~194 µs: op-count and critical-path A/Bs (R3/R4/R5) all ~0 effect;
// occupancy is the only sensitive axis (R3). Grid (289, 32) = measured best.
__global__ __launch_bounds__(256) void k_prefilter(const uint32_t* __restrict__ bth,
                                                   int* __restrict__ svcnt,
                                                   uint2* __restrict__ svrec) {
    int c = blockIdx.x * 256 + threadIdx.x;   // 289*256 == CCLS exactly
    int k0 = blockIdx.y * (KSMP / ROWG);
    uint32_t th = bth[c];
    uint32_t i = (uint32_t)k0 * (uint32_t)CCLS + (uint32_t)c;
#pragma unroll 4
    for (int kk = 0; kk < KSMP / ROWG; ++kk) {
        uint32_t bits = tf_bits(i);
        if (__builtin_expect(bits >= th, 0)) {
            int row = k0 + kk;
            int idx = atomicAdd(&svcnt[row], 1);
            if (idx < SVCAP) svrec[row * SVCAP + idx] = make_uint2((uint32_t)c, bits);
        }
        i += (uint32_t)CCLS;
    }
}

// ---------------- K3f: per-row exact eval + argmax (1 wave/row) + fused table insert ----------------
__global__ __launch_bounds__(64) void k_finalize(const float* __restrict__ logits,
                                                 const int* __restrict__ svcnt,
                                                 const uint2* __restrict__ svrec,
                                                 const int* __restrict__ yidx,
                                                 int* __restrict__ hkeys,
                                                 int* __restrict__ samples) {
    int k = blockIdx.x;
    int tid = threadIdx.x;   // 64 threads = 1 wave
    int n = svcnt[k];
    float best = -INFINITY; int bc = 0x7fffffff;
    if (n > 0 && n <= SVCAP) {
        if (tid < n) {
            uint2 rec = svrec[k * SVCAP + tid];
            int c = (int)rec.x;
            best = __fadd_rn(gumbel_from_u(uniform_from_bits(rec.y)), logits[c]);
            bc = c;
        }
    } else {
        // empty (P ~ e^-21) or overflow (Poisson(21) tail @64): exact full scan
        uint32_t base = (uint32_t)k * (uint32_t)CCLS;
        for (int c = tid; c < CCLS; c += 64) {
            float v = __fadd_rn(gumbel_from_u(uniform_from_bits(tf_bits(base + (uint32_t)c))), logits[c]);
            if (v > best || (v == best && c < bc)) { best = v; bc = c; }
        }
    }
    // wave butterfly reduce on (max, min-index) — order-independent predicate
    for (int off = 32; off > 0; off >>= 1) {
        float v2 = __shfl_down(best, off);
        int   i2 = __shfl_down(bc, off);
        if (v2 > best || (v2 == best && i2 < bc)) { best = v2; bc = i2; }
    }
    if (tid == 0) {
        samples[k] = bc;
        // fused hash-table insert (hkeys pre-initialized to -1 via memset 0xFF)
        int xi = bc / GZD, zi = bc % GZD;
        int yi = yidx[bc];
        int flat = (xi*GYD + yi)*GZD + zi;
        uint32_t h = cell_hash(flat);
        for (;;) {
            int prev = atomicCAS(&hkeys[h], -1, flat);
            if (prev == -1 || prev == flat) break;
            h = (h + 1) & (HSLOTS - 1);
        }
    }
}

// ---------------- K3c: replay votes (all 36 rots per thread), accumulate scale sums ----------------
__global__ __launch_bounds__(256) void k_scale_scatter(const float* __restrict__ pc, const float* __restrict__ xyz,
                          const float* __restrict__ scale, const float* __restrict__ prob,
                          const float* __restrict__ corners,
                          const int* __restrict__ hkeys, float* __restrict__ gsmall,
                          int N, RotTab rt) {
    __shared__ int lk[HSLOTS];
    for (int j = threadIdx.x; j < HSLOTS; j += 256) lk[j] = hkeys[j];
    __syncthreads();
    int i = blockIdx.x * 256 + threadIdx.x;
    if (i >= N) return;
    float px = pc[3*i], py = pc[3*i+1], pz = pc[3*i+2];
    float ox = xyz[3*i], oy = xyz[3*i+1], oz = xyz[3*i+2];
    int iy;
    if (!vote_iy(py, oy, corners[1], iy)) return;
    float c0x = corners[0], c0z = corners[2];
    int iyo = iy * GZD;
    float w0 = prob[i];
    float ws0 = __fmul_rn(w0, scale[3*i]);
    float ws1 = __fmul_rn(w0, scale[3*i+1]);
    float ws2 = __fmul_rn(w0, scale[3*i+2]);
    for (int r = 0; r < NROT; ++r) {
        int ix, iz;
        if (!vote_xz(px, pz, ox, oz, rt.c[r], rt.s[r], c0x, c0z, ix, iz)) continue;
        int flat = ix * SLICE + iyo + iz;
        uint32_t h = cell_hash(flat);
        int slot = -1;
        for (;;) {
            int key = lk[h];
            if (key == flat) { slot = (int)h; break; }
            if (key == -1) break;
            h = (h + 1) & (HSLOTS - 1);
        }
        if (slot < 0) continue;
        atomicAdd(&gsmall[3*slot+0], ws0);
        atomicAdd(&gsmall[3*slot+1], ws1);
        atomicAdd(&gsmall[3*slot+2], ws2);
    }
}

// ---------------- K4: one block per sample — world loc, scale, keep ----------------
__global__ __launch_bounds__(256) void k_post(const float* __restrict__ gobj,
                       const int* __restrict__ hkeys, const float* __restrict__ gsmall,
                       const int* __restrict__ yidx, const int* __restrict__ samples,
                       const float* __restrict__ corners, const float* __restrict__ vp, int M,
                       float* __restrict__ world, float* __restrict__ scv, int* __restrict__ keep) {
    int k = blockIdx.x;
    int tid = threadIdx.x;
    int s = samples[k];
    int xi = s / GZD, zi = s % GZD;
    int yi = yidx[s];
    float wx = __fadd_rn(__fmul_rn((float)xi, 0.03f), corners[0]);
    float wy = __fadd_rn(__fmul_rn((float)yi, 0.03f), corners[1]);
    float wz = __fadd_rn(__fmul_rn((float)zi, 0.03f), corners[2]);

    float dmin = INFINITY;
    for (int j = tid; j < M; j += 256) {
        float dx = __fsub_rn(wx, vp[3*j]);
        float dy = __fsub_rn(wy, vp[3*j+1]);
        float dz = __fsub_rn(wz, vp[3*j+2]);
        float sq = __fadd_rn(__fadd_rn(__fmul_rn(dx,dx), __fmul_rn(dy,dy)), __fmul_rn(dz,dz));
        dmin = fminf(dmin, __fsqrt_rn(sq));
    }
    __shared__ float sm[256];
    sm[tid] = dmin; __syncthreads();
    for (int off = 128; off > 0; off >>= 1) {
        if (tid < off) sm[tid] = fminf(sm[tid], sm[tid+off]);
        __syncthreads();
    }
    if (tid == 0) {
        world[3*k] = wx; world[3*k+1] = wy; world[3*k+2] = wz;
        int flat = (xi*GYD + yi)*GZD + zi;
        uint32_t h = cell_hash(flat);
        while (hkeys[h] != flat) h = (h + 1) & (HSLOTS - 1);  // guaranteed present
        float go = __fadd_rn(gobj[flat], 1e-7f);
        scv[3*k+0] = __fdiv_rn(gsmall[3*h+0], go);
        scv[3*k+1] = __fdiv_rn(gsmall[3*h+1], go);
        scv[3*k+2] = __fdiv_rn(gsmall[3*h+2], go);
        keep[k] = (sm[0] < 0.3f) ? 1 : 0;
    }
}

// ---------------- K5: stable 0/1 selection via parallel prefix-sum ----------------
__global__ __launch_bounds__(256) void k_select(const float* __restrict__ world,
                                                const float* __restrict__ scv,
                                                const int* __restrict__ keep,
                                                float* __restrict__ out) {
    __shared__ int kp[KSMP];
    __shared__ int tsum[256];
    __shared__ int sel[NPROP];
    __shared__ int anyk;
    int tid = threadIdx.x;
    if (tid == 0) anyk = 0;
    __syncthreads();
    int a = 0;
    for (int j = tid; j < KSMP; j += 256) { int v = keep[j]; kp[j] = v; a |= v; }
    if (a) anyk = 1;           // benign race, all writers store 1
    __syncthreads();
    int any = anyk;
    int j0 = tid * 4;
    int k0v = any ? kp[j0]   : 1;
    int k1v = any ? kp[j0+1] : 1;
    int k2v = any ? kp[j0+2] : 1;
    int k3v = any ? kp[j0+3] : 1;
    int s0 = k0v, s1 = s0 + k1v, s2 = s1 + k2v, s3 = s2 + k3v;
    tsum[tid] = s3;
    __syncthreads();
    for (int off = 1; off < 256; off <<= 1) {
        int x = tsum[tid];
        if (tid >= off) x += tsum[tid - off];
        __syncthreads();
        tsum[tid] = x;
        __syncthreads();
    }
    int base = (tid > 0) ? tsum[tid-1] : 0;
    int nk = tsum[255];  // total kept
    int inc[4] = { base + s0, base + s1, base + s2, base + s3 };
    int kv[4]  = { k0v, k1v, k2v, k3v };
    for (int q = 0; q < 4; ++q) {
        int j = j0 + q;
        int slot = kv[q] ? (inc[q] - 1) : (nk + j - inc[q]);
        if (slot < NPROP) sel[slot] = j;
    }
    __syncthreads();
    if (tid < NPROP) {
        int sidx = sel[tid];
        out[3*tid+0] = world[3*sidx+0];
        out[3*tid+1] = world[3*sidx+1];
        out[3*tid+2] = world[3*sidx+2];
        out[3*NPROP + tid] = 0.0f;                 // probs
        out[4*NPROP + 3*tid + 0] = scv[3*sidx+0];
        out[4*NPROP + 3*tid + 1] = scv[3*sidx+1];
        out[4*NPROP + 3*tid + 2] = scv[3*sidx+2];
    }
}

extern "C" void kernel_launch(void* const* d_in, const int* in_sizes, int n_in,
                              void* d_out, int out_size, void* d_ws, size_t ws_size,
                              hipStream_t stream) {
    const float* pc      = (const float*)d_in[0];
    const float* xyz     = (const float*)d_in[1];
    const float* scale   = (const float*)d_in[2];
    const float* prob    = (const float*)d_in[3];
    const float* corners = (const float*)d_in[4];
    const float* vp      = (const float*)d_in[5];
    int N = in_sizes[0] / 3;
    int M = in_sizes[5] / 3;
    int NV = N * NROT;
    int pblocks = (N + 255) / 256;

    const size_t G = (size_t)GXD * GYD * GZD;  // 8,286,208
    float* gobj    = (float*)d_ws;
    // ---- zeroed region (single memset): sumdist, bincnt, svcnt, pad, packed, gsmall ----
    float* sumdist = gobj + G;                         // 1
    int*   bincnt  = (int*)(sumdist + 1);              // NBINS
    int*   svcnt   = bincnt + NBINS;                   // KSMP
    // pad 1 int so packed is 8-byte aligned: (1+544+1024+1)*4 = 6280 B, 8 | 6280
    unsigned long long* packed = (unsigned long long*)(svcnt + KSMP + 1);  // CCLS u64
    float* gsmall  = (float*)(packed + CCLS);          // 3*HSLOTS
    size_t zero_bytes = (size_t)((char*)(gsmall + 3*HSLOTS) - (char*)sumdist);
    // ---- rest ----
    int*   binbase = (int*)(gsmall + 3*HSLOTS);
    int*   bincur  = binbase + NBINS;
    float* logits  = (float*)(bincur + NBINS);
    uint32_t* bth  = (uint32_t*)(logits + CCLS);
    int*   yidx    = (int*)(bth + CCLS);
    int*   samples = yidx + CCLS;
    int*   hkeys   = samples + KSMP;                   // memset 0xFF
    float* world   = (float*)(hkeys + HSLOTS);
    float* scv     = world + 3*KSMP;
    int*   keep    = (int*)(scv + 3*KSMP);
    uint2* svrec   = (uint2*)(((uintptr_t)(keep + KSMP) + 15) & ~(uintptr_t)15);
    int*   hblk    = (int*)(svrec + (size_t)KSMP * SVCAP);   // pblocks*NBINS
    uint2* vrec    = (uint2*)(((uintptr_t)(hblk + (size_t)pblocks*NBINS) + 15) & ~(uintptr_t)15);
    size_t need = (size_t)((char*)(vrec + NV) - (char*)d_ws);
    if (ws_size < need) {
        fprintf(stderr, "kernel_launch: ws_size %zu < needed %zu\n", ws_size, need);
        return;
    }

    hipMemsetAsync(sumdist, 0, zero_bytes, stream);            // ~623 KB
    hipMemsetAsync(hkeys, 0xFF, HSLOTS*sizeof(int), stream);   // hkeys = -1

    // rotation table: f32 theta chain exactly as reference, cos/sin in double -> f32
    RotTab rt;
    const float twopi = (float)(2.0 * M_PI);
    for (int r = 0; r < NROT; ++r) {
        float th = (twopi * (float)r) / 36.0f;
        rt.c[r] = (float)cos((double)th);
        rt.s[r] = (float)sin((double)th);
    }

    k_count<<<pblocks, 256, 0, stream>>>(pc, xyz, corners, N, rt, bincnt, hblk);
    k_prefix<<<1, 576, 0, stream>>>(bincnt, binbase, bincur);
    k_binwrite<<<pblocks, 256, 0, stream>>>(pc, xyz, prob, corners, N, rt, bincur, hblk, vrec);
    k_accum<<<NBINS, 256, 0, stream>>>(binbase, bincnt, vrec, gobj, packed);
    k_colmax2<<<CCLS / 256, 256, 0, stream>>>(packed, logits, yidx, sumdist);
    k_thresh<<<CCLS / 256, 256, 0, stream>>>(logits, sumdist, bth);
    dim3 pf_grid(CCLS / 256, ROWG);
    k_prefilter<<<pf_grid, 256, 0, stream>>>(bth, svcnt, svrec);
    k_finalize<<<KSMP, 64, 0, stream>>>(logits, svcnt, svrec, yidx, hkeys, samples);
    k_scale_scatter<<<pblocks, 256, 0, stream>>>(pc, xyz, scale, prob, corners, hkeys, gsmall, N, rt);
    k_post<<<KSMP, 256, 0, stream>>>(gobj, hkeys, gsmall, yidx, samples, corners, vp, M, world, scv, keep);
    k_select<<<1, 256, 0, stream>>>(world, scv, keep, (float*)d_out);
}

// Round 7
// 369.122 us; speedup vs baseline: 1.0880x; 1.0662x over previous
//
#include <hip/hip_runtime.h>
#include <math.h>
#include <stdio.h>
#include <stdint.h>

#define GXD 272
#define GYD 112
#define GZD 272
#define NROT 36
#define CCLS (GXD*GZD)     /* 73984 = 289*256 */
#define CBLK (CCLS/256)    /* 289 cell blocks */
#define KSMP 1024          /* NUM_PROPOSAL*OVERSAMPLE */
#define NPROP 256
#define HSLOTS 2048        /* sampled-cell hash table slots */
#define YH 56              /* y-half size */
#define NBINS (GXD*2)      /* 544: (x-slice, y-half) bins */
#define SLICE (GYD*GZD)    /* 30464 cells per x-slice */
#define SVCAP 96           /* survivor capacity per row (spec E~36) */
#define AROWS 32           /* rows per phase-A unit */
#define AUNITS (CBLK * (KSMP/AROWS))   /* 289*32 = 9248 ballast units */
#define TH_SPEC 0xFFE00000u  /* speculative bits threshold: p = 2^-11 */

struct RotTab { float c[NROT]; float s[NROT]; };

__device__ __forceinline__ uint32_t cell_hash(int flat) {
    return ((uint32_t)flat * 2654435761u) >> 21;  // top 11 bits -> 0..2047
}

// rotl via single v_alignbit_b32: alignbit(x,x,s) = rotr(x,s); rotl(x,r)=rotr(x,32-r)
#define ROTL_AB(x, r) __builtin_amdgcn_alignbit((x), (x), 32u - (r))

// ---------------- threefry2x32, key (0,42), counter (0,i), out = o0^o1 ----------------
// JAX partitionable random_bits semantics (verified bit-exact across rounds).
__device__ __forceinline__ uint32_t tf_bits(uint32_t i) {
    constexpr uint32_t K1  = 42u;
    constexpr uint32_t KS2 = 42u ^ 0x1BD11BDAu;
    uint32_t x0 = 0u, x1 = i + K1;                     // inj0 (k0 == 0)
#define TF_R(r)  { x0 += x1; x1 = ROTL_AB(x1, r); x1 ^= x0; }
#define TF_RI(r, I0, I1) { x1 += (I1); x0 = x0 + (I0) + x1; x1 = ROTL_AB(x1, r); x1 ^= x0; }
    TF_R(13) TF_R(15) TF_R(26) TF_R(6)
    TF_RI(17, K1,  KS2 + 1u)  TF_R(29) TF_R(16) TF_R(24)
    TF_RI(13, KS2, 2u)        TF_R(15) TF_R(26) TF_R(6)
    TF_RI(17, 0u,  K1 + 3u)   TF_R(29) TF_R(16) TF_R(24)
    TF_RI(13, K1,  KS2 + 4u)  TF_R(15) TF_R(26) TF_R(6)
#undef TF_R
#undef TF_RI
    return (x0 + KS2) ^ (x1 + 5u);                     // inj5 folded into output
}

__device__ __forceinline__ float uniform_from_bits(uint32_t b) {
    const float TINY = 1.1754943508222875e-38f; // np.finfo(float32).tiny
    float f = __uint_as_float((b >> 9) | 0x3f800000u) - 1.0f;
    float u = __fadd_rn(__fmul_rn(f, 1.0f), TINY);
    return fmaxf(TINY, u);
}

// gumbel = -log(-log(u)); f32 logs via double rounding (== correctly-rounded logf)
__device__ __forceinline__ float gumbel_from_u(float u) {
    float l1 = (float)log((double)u);
    float l2 = (float)log((double)(-l1));
    return -l2;
}

// ---------------- Phase A: speculative survivor recording (data-independent) ----------------
// unit -> (cell block cb, row group rg). Records (c, bits) with bits >= TH_SPEC.
// Record order is irrelevant (finalize argmax is order-independent); counts atomic.
__device__ __forceinline__ void phaseA_unit(int unit, int* __restrict__ svcnt,
                                            uint2* __restrict__ svrec) {
    int cb = unit % CBLK;
    int rg = unit / CBLK;
    int c  = cb * 256 + threadIdx.x;
    int k0 = rg * AROWS;
    uint32_t i = (uint32_t)k0 * (uint32_t)CCLS + (uint32_t)c;
#pragma unroll 4
    for (int kk = 0; kk < AROWS; ++kk) {
        uint32_t bits = tf_bits(i);
        if (__builtin_expect(bits >= TH_SPEC, 0)) {
            int row = k0 + kk;
            int idx = atomicAdd(&svcnt[row], 1);
            if (idx < SVCAP) svrec[row * SVCAP + idx] = make_uint2((uint32_t)c, bits);
        }
        i += (uint32_t)CCLS;
    }
}

// ---- vote voxel helpers: MUST stay bit-identical across all passes ----
__device__ __forceinline__ bool vote_iy(float py, float oy, float c0y, int& iy) {
    float ty = __fadd_rn(py, oy);
    float vy = __fadd_rn(__fdiv_rn(__fsub_rn(ty, c0y), 0.03f), 0.5f);
    iy = (int)floorf(vy);
    return (iy >= 0 && iy < GYD);
}
__device__ __forceinline__ bool vote_xz(float px, float pz, float ox, float oz,
                                        float c, float s, float c0x, float c0z,
                                        int& ix, int& iz) {
    float rx = __fadd_rn(__fmul_rn(ox, c), __fmul_rn(oz, s));
    float rz = __fadd_rn(__fmul_rn(-ox, s), __fmul_rn(oz, c));
    float tx = __fadd_rn(px, rx);
    float tz = __fadd_rn(pz, rz);
    float vx = __fadd_rn(__fdiv_rn(__fsub_rn(tx, c0x), 0.03f), 0.5f);
    float vz = __fadd_rn(__fdiv_rn(__fsub_rn(tz, c0z), 0.03f), 0.5f);
    ix = (int)floorf(vx);
    iz = (int)floorf(vz);
    return (ix >= 0 && ix < GXD && iz >= 0 && iz < GZD);
}

// ---------------- K1a: count votes per bin + cache per-block hist  [+ phase-A ballast] ----------------
__global__ __launch_bounds__(256) void k_count_b(const float* __restrict__ pc, const float* __restrict__ xyz,
                          const float* __restrict__ corners, int N, RotTab rt,
                          int* __restrict__ bincnt, int* __restrict__ hblk,
                          int nOrig, int unitBase, int* __restrict__ svcnt, uint2* __restrict__ svrec) {
    if ((int)blockIdx.x >= nOrig) { phaseA_unit(unitBase + (int)blockIdx.x - nOrig, svcnt, svrec); return; }
    __shared__ int h[NBINS];
    int tid = threadIdx.x;
    for (int j = tid; j < NBINS; j += 256) h[j] = 0;
    __syncthreads();
    int i = blockIdx.x * 256 + tid;
    if (i < N) {
        float px = pc[3*i], py = pc[3*i+1], pz = pc[3*i+2];
        float ox = xyz[3*i], oy = xyz[3*i+1], oz = xyz[3*i+2];
        int iy;
        if (vote_iy(py, oy, corners[1], iy)) {
            int ybit = (iy >= YH) ? 1 : 0;
            float c0x = corners[0], c0z = corners[2];
            for (int r = 0; r < NROT; ++r) {
                int ix, iz;
                if (vote_xz(px, pz, ox, oz, rt.c[r], rt.s[r], c0x, c0z, ix, iz))
                    atomicAdd(&h[ix*2 + ybit], 1);
            }
        }
    }
    __syncthreads();
    int* hb = hblk + (size_t)blockIdx.x * NBINS;
    for (int j = tid; j < NBINS; j += 256) {
        int cnt = h[j];
        hb[j] = cnt;
        if (cnt) atomicAdd(&bincnt[j], cnt);
    }
}

// ---------------- K1b: parallel exclusive scan over 544 bins ----------------
__global__ __launch_bounds__(576) void k_prefix(const int* __restrict__ bincnt,
                         int* __restrict__ binbase, int* __restrict__ bincur) {
    __shared__ int sc[576];
    int tid = threadIdx.x;
    int v = (tid < NBINS) ? bincnt[tid] : 0;
    sc[tid] = v;
    __syncthreads();
    for (int off = 1; off < 576; off <<= 1) {
        int x = sc[tid];
        if (tid >= off) x += sc[tid - off];
        __syncthreads();
        sc[tid] = x;
        __syncthreads();
    }
    if (tid < NBINS) {
        int excl = sc[tid] - v;
        binbase[tid] = excl;
        bincur[tid] = excl;
    }
}

// ---------------- K1c: write vote records binned  [+ phase-A ballast] ----------------
__global__ __launch_bounds__(256) void k_binwrite_b(const float* __restrict__ pc, const float* __restrict__ xyz,
                          const float* __restrict__ prob, const float* __restrict__ corners,
                          int N, RotTab rt, int* __restrict__ bincur,
                          const int* __restrict__ hblk, uint2* __restrict__ vrec,
                          int nOrig, int unitBase, int* __restrict__ svcnt, uint2* __restrict__ svrec) {
    if ((int)blockIdx.x >= nOrig) { phaseA_unit(unitBase + (int)blockIdx.x - nOrig, svcnt, svrec); return; }
    __shared__ int h[NBINS];      // local rank cursor
    __shared__ int bbase[NBINS];  // this block's base per bin
    int tid = threadIdx.x;
    const int* hb = hblk + (size_t)blockIdx.x * NBINS;
    for (int j = tid; j < NBINS; j += 256) {
        int cnt = hb[j];
        bbase[j] = cnt ? atomicAdd(&bincur[j], cnt) : 0;
        h[j] = 0;
    }
    __syncthreads();
    int i = blockIdx.x * 256 + tid;
    if (i < N) {
        float px = pc[3*i], py = pc[3*i+1], pz = pc[3*i+2];
        float ox = xyz[3*i], oy = xyz[3*i+1], oz = xyz[3*i+2];
        int iy;
        if (vote_iy(py, oy, corners[1], iy)) {
            int ybit = (iy >= YH) ? 1 : 0;
            float c0x = corners[0], c0z = corners[2];
            float w0 = prob[i];
            for (int r = 0; r < NROT; ++r) {
                int ix, iz;
                if (vote_xz(px, pz, ox, oz, rt.c[r], rt.s[r], c0x, c0z, ix, iz)) {
                    int bin = ix*2 + ybit;
                    int rank = atomicAdd(&h[bin], 1);
                    int slot = bbase[bin] + rank;
                    vrec[slot] = make_uint2((uint32_t)((ix*GYD + iy)*GZD + iz), __float_as_uint(w0));
                }
            }
        }
    }
}

// ---------------- K1d: per-bin LDS accumulate -> gobj + packed column-max atomicMax ----------------
// (no ballast: 61KB LDS would cap ballast occupancy)
__global__ __launch_bounds__(256) void k_accum(const int* __restrict__ binbase,
                          const int* __restrict__ bincnt,
                          const uint2* __restrict__ vrec,
                          float* __restrict__ gobj,
                          unsigned long long* __restrict__ packed) {
    __shared__ float tile[YH*GZD];   // 56*272*4 = 60928 B
    int b = blockIdx.x;
    int x = b >> 1, yh = b & 1;
    int tid = threadIdx.x;
    for (int j = tid; j < YH*GZD; j += 256) tile[j] = 0.0f;
    __syncthreads();
    int lo = binbase[b], n = bincnt[b];
    int xoff = x * SLICE;
    int yoff = yh * (YH*GZD);
    int sub = xoff + yoff;
    for (int j = lo + tid; j < lo + n; j += 256) {
        uint2 rec = vrec[j];
        atomicAdd(&tile[(int)rec.x - sub], __uint_as_float(rec.y));
    }
    __syncthreads();
    float* dst = gobj + (size_t)sub;
    for (int j = tid; j < YH*GZD; j += 256) dst[j] = tile[j];
    int ybase = yh * YH;
    for (int z = tid; z < GZD; z += 256) {
        float m = tile[z];
        int mi = 0;
        for (int y = 1; y < YH; ++y) {
            float v = tile[y*GZD + z];
            if (v > m) { m = v; mi = y; }
        }
        unsigned long long key = ((unsigned long long)__float_as_uint(m) << 32)
                               | (unsigned long long)(uint32_t)(0x7F - (ybase + mi));
        atomicMax(&packed[x*GZD + z], key);
    }
}

// ---------------- K2: decode packed -> logits/yidx; sum(dist)  [+ phase-A ballast] ----------------
__global__ __launch_bounds__(256) void k_colmax2_b(const unsigned long long* __restrict__ packed,
                         float* __restrict__ logits, int* __restrict__ yidx,
                         float* __restrict__ sumdist,
                         int nOrig, int unitBase, int* __restrict__ svcnt, uint2* __restrict__ svrec) {
    if ((int)blockIdx.x >= nOrig) { phaseA_unit(unitBase + (int)blockIdx.x - nOrig, svcnt, svrec); return; }
    int c = blockIdx.x * 256 + threadIdx.x;
    unsigned long long key = packed[c];
    float m = __uint_as_float((uint32_t)(key >> 32));
    int mi = 0x7F - (int)(uint32_t)(key & 0xFFFFFFFFu);
    float d = __fsqrt_rn(__fadd_rn(m, 1e-7f));
    yidx[c] = mi;
    logits[c] = (float)log((double)__fadd_rn(d, 1e-30f));
    __shared__ float sred[256];
    int tid = threadIdx.x;
    sred[tid] = d; __syncthreads();
    for (int off = 128; off > 0; off >>= 1) {
        if (tid < off) sred[tid] += sred[tid+off];
        __syncthreads();
    }
    if (tid == 0) atomicAdd(sumdist, sred[0]);
}

// ---------------- K2b: bth + hot-cell list  [+ phase-A ballast] ----------------
// bth construction unchanged (over-includes vs exact v > B0-0.05). Hot cells
// (bth < TH_SPEC) need phase-B retesting for bits in [bth, TH_SPEC).
__global__ __launch_bounds__(256) void k_hotthresh_b(const float* __restrict__ logits,
                                                     const float* __restrict__ sumdist,
                                                     uint32_t* __restrict__ bth,
                                                     int* __restrict__ hotcnt, int* __restrict__ hotlist,
                                                     int nOrig, int unitBase,
                                                     int* __restrict__ svcnt, uint2* __restrict__ svrec) {
    if ((int)blockIdx.x >= nOrig) { phaseA_unit(unitBase + (int)blockIdx.x - nOrig, svcnt, svrec); return; }
    int c = blockIdx.x * 256 + threadIdx.x;
    double B0 = log((double)*sumdist) - 3.0;
    double t = exp(-exp((double)logits[c] - (B0 - 0.05)));
    long long k_th = (long long)floor(t * 8388608.0) - 2;
    uint32_t b;
    if (k_th <= 0)              b = 0u;           // everything survives
    else if (k_th >= 8388608LL) b = 0xFFFFFFFFu;  // ~nothing survives (over-include, harmless)
    else                        b = (uint32_t)k_th << 9;
    bth[c] = b;
    if (b < TH_SPEC) {
        int idx = atomicAdd(hotcnt, 1);
        hotlist[idx] = c;
    }
}

// ---------------- K3b: phase-B exact retest of hot cells (disjoint band bits < TH_SPEC) ----------------
__global__ __launch_bounds__(256) void k_phaseB(const uint32_t* __restrict__ bth,
                                                const int* __restrict__ hotlist,
                                                const int* __restrict__ hotcnt,
                                                int* __restrict__ svcnt, uint2* __restrict__ svrec) {
    int k = blockIdx.x;
    int n = *hotcnt;
    uint32_t base = (uint32_t)k * (uint32_t)CCLS;
    for (int j = threadIdx.x; j < n; j += 256) {
        int c = hotlist[j];
        uint32_t bits = tf_bits(base + (uint32_t)c);
        if (bits >= bth[c] && bits < TH_SPEC) {
            int idx = atomicAdd(&svcnt[k], 1);
            if (idx < SVCAP) svrec[k * SVCAP + idx] = make_uint2((uint32_t)c, bits);
        }
    }
}

// ---------------- K3f: per-row argmax over records, exactness-checked + fused table insert ----------------
// Fallback to exact full scan when: no records, overflow, or best <= B0-0.05
// (the guarantee "v > B0-0.05 => recorded" makes this exact, not probabilistic).
__global__ __launch_bounds__(64) void k_finalize(const float* __restrict__ logits,
                                                 const float* __restrict__ sumdist,
                                                 const int* __restrict__ svcnt,
                                                 const uint2* __restrict__ svrec,
                                                 const int* __restrict__ yidx,
                                                 int* __restrict__ hkeys,
                                                 int* __restrict__ samples) {
    int k = blockIdx.x;
    int tid = threadIdx.x;   // 64 threads = 1 wave
    int n = svcnt[k];
    float best = -INFINITY; int bc = 0x7fffffff;
    bool full = (n <= 0 || n > SVCAP);
    if (!full) {
        for (int j = tid; j < n; j += 64) {
            uint2 rec = svrec[k * SVCAP + j];
            int c = (int)rec.x;
            float v = __fadd_rn(gumbel_from_u(uniform_from_bits(rec.y)), logits[c]);
            if (v > best || (v == best && c < bc)) { best = v; bc = c; }
        }
        // xor-butterfly: all lanes end with (max, min-index)
        for (int off = 32; off > 0; off >>= 1) {
            float v2 = __shfl_xor(best, off);
            int   i2 = __shfl_xor(bc, off);
            if (v2 > best || (v2 == best && i2 < bc)) { best = v2; bc = i2; }
        }
        double B0 = log((double)*sumdist) - 3.0;
        if (!((double)best > B0 - 0.05)) full = true;   // winner might be unrecorded
    }
    if (full) {
        best = -INFINITY; bc = 0x7fffffff;
        uint32_t base = (uint32_t)k * (uint32_t)CCLS;
        for (int c = tid; c < CCLS; c += 64) {
            float v = __fadd_rn(gumbel_from_u(uniform_from_bits(tf_bits(base + (uint32_t)c))), logits[c]);
            if (v > best || (v == best && c < bc)) { best = v; bc = c; }
        }
        for (int off = 32; off > 0; off >>= 1) {
            float v2 = __shfl_xor(best, off);
            int   i2 = __shfl_xor(bc, off);
            if (v2 > best || (v2 == best && i2 < bc)) { best = v2; bc = i2; }
        }
    }
    if (tid == 0) {
        samples[k] = bc;
        // fused hash-table insert (hkeys pre-initialized to -1 via memset 0xFF)
        int xi = bc / GZD, zi = bc % GZD;
        int yi = yidx[bc];
        int flat = (xi*GYD + yi)*GZD + zi;
        uint32_t h = cell_hash(flat);
        for (;;) {
            int prev = atomicCAS(&hkeys[h], -1, flat);
            if (prev == -1 || prev == flat) break;
            h = (h + 1) & (HSLOTS - 1);
        }
    }
}

// ---------------- K3c: replay votes (all 36 rots per thread), accumulate scale sums ----------------
__global__ __launch_bounds__(256) void k_scale_scatter(const float* __restrict__ pc, const float* __restrict__ xyz,
                          const float* __restrict__ scale, const float* __restrict__ prob,
                          const float* __restrict__ corners,
                          const int* __restrict__ hkeys, float* __restrict__ gsmall,
                          int N, RotTab rt) {
    __shared__ int lk[HSLOTS];
    for (int j = threadIdx.x; j < HSLOTS; j += 256) lk[j] = hkeys[j];
    __syncthreads();
    int i = blockIdx.x * 256 + threadIdx.x;
    if (i >= N) return;
    float px = pc[3*i], py = pc[3*i+1], pz = pc[3*i+2];
    float ox = xyz[3*i], oy = xyz[3*i+1], oz = xyz[3*i+2];
    int iy;
    if (!vote_iy(py, oy, corners[1], iy)) return;
    float c0x = corners[0], c0z = corners[2];
    int iyo = iy * GZD;
    float w0 = prob[i];
    float ws0 = __fmul_rn(w0, scale[3*i]);
    float ws1 = __fmul_rn(w0, scale[3*i+1]);
    float ws2 = __fmul_rn(w0, scale[3*i+2]);
    for (int r = 0; r < NROT; ++r) {
        int ix, iz;
        if (!vote_xz(px, pz, ox, oz, rt.c[r], rt.s[r], c0x, c0z, ix, iz)) continue;
        int flat = ix * SLICE + iyo + iz;
        uint32_t h = cell_hash(flat);
        int slot = -1;
        for (;;) {
            int key = lk[h];
            if (key == flat) { slot = (int)h; break; }
            if (key == -1) break;
            h = (h + 1) & (HSLOTS - 1);
        }
        if (slot < 0) continue;
        atomicAdd(&gsmall[3*slot+0], ws0);
        atomicAdd(&gsmall[3*slot+1], ws1);
        atomicAdd(&gsmall[3*slot+2], ws2);
    }
}

// ---------------- K4: one block per sample — world loc, scale, keep ----------------
__global__ __launch_bounds__(256) void k_post(const float* __restrict__ gobj,
                       const int* __restrict__ hkeys, const float* __restrict__ gsmall,
                       const int* __restrict__ yidx, const int* __restrict__ samples,
                       const float* __restrict__ corners, const float* __restrict__ vp, int M,
                       float* __restrict__ world, float* __restrict__ scv, int* __restrict__ keep) {
    int k = blockIdx.x;
    int tid = threadIdx.x;
    int s = samples[k];
    int xi = s / GZD, zi = s % GZD;
    int yi = yidx[s];
    float wx = __fadd_rn(__fmul_rn((float)xi, 0.03f), corners[0]);
    float wy = __fadd_rn(__fmul_rn((float)yi, 0.03f), corners[1]);
    float wz = __fadd_rn(__fmul_rn((float)zi, 0.03f), corners[2]);

    float dmin = INFINITY;
    for (int j = tid; j < M; j += 256) {
        float dx = __fsub_rn(wx, vp[3*j]);
        float dy = __fsub_rn(wy, vp[3*j+1]);
        float dz = __fsub_rn(wz, vp[3*j+2]);
        float sq = __fadd_rn(__fadd_rn(__fmul_rn(dx,dx), __fmul_rn(dy,dy)), __fmul_rn(dz,dz));
        dmin = fminf(dmin, __fsqrt_rn(sq));
    }
    __shared__ float sm[256];
    sm[tid] = dmin; __syncthreads();
    for (int off = 128; off > 0; off >>= 1) {
        if (tid < off) sm[tid] = fminf(sm[tid], sm[tid+off]);
        __syncthreads();
    }
    if (tid == 0) {
        world[3*k] = wx; world[3*k+1] = wy; world[3*k+2] = wz;
        int flat = (xi*GYD + yi)*GZD + zi;
        uint32_t h = cell_hash(flat);
        while (hkeys[h] != flat) h = (h + 1) & (HSLOTS - 1);  // guaranteed present
        float go = __fadd_rn(gobj[flat], 1e-7f);
        scv[3*k+0] = __fdiv_rn(gsmall[3*h+0], go);
        scv[3*k+1] = __fdiv_rn(gsmall[3*h+1], go);
        scv[3*k+2] = __fdiv_rn(gsmall[3*h+2], go);
        keep[k] = (sm[0] < 0.3f) ? 1 : 0;
    }
}

// ---------------- K5: stable 0/1 selection via parallel prefix-sum ----------------
__global__ __launch_bounds__(256) void k_select(const float* __restrict__ world,
                                                const float* __restrict__ scv,
                                                const int* __restrict__ keep,
                                                float* __restrict__ out) {
    __shared__ int kp[KSMP];
    __shared__ int tsum[256];
    __shared__ int sel[NPROP];
    __shared__ int anyk;
    int tid = threadIdx.x;
    if (tid == 0) anyk = 0;
    __syncthreads();
    int a = 0;
    for (int j = tid; j < KSMP; j += 256) { int v = keep[j]; kp[j] = v; a |= v; }
    if (a) anyk = 1;           // benign race, all writers store 1
    __syncthreads();
    int any = anyk;
    int j0 = tid * 4;
    int k0v = any ? kp[j0]   : 1;
    int k1v = any ? kp[j0+1] : 1;
    int k2v = any ? kp[j0+2] : 1;
    int k3v = any ? kp[j0+3] : 1;
    int s0 = k0v, s1 = s0 + k1v, s2 = s1 + k2v, s3 = s2 + k3v;
    tsum[tid] = s3;
    __syncthreads();
    for (int off = 1; off < 256; off <<= 1) {
        int x = tsum[tid];
        if (tid >= off) x += tsum[tid - off];
        __syncthreads();
        tsum[tid] = x;
        __syncthreads();
    }
    int base = (tid > 0) ? tsum[tid-1] : 0;
    int nk = tsum[255];  // total kept
    int inc[4] = { base + s0, base + s1, base + s2, base + s3 };
    int kv[4]  = { k0v, k1v, k2v, k3v };
    for (int q = 0; q < 4; ++q) {
        int j = j0 + q;
        int slot = kv[q] ? (inc[q] - 1) : (nk + j - inc[q]);
        if (slot < NPROP) sel[slot] = j;
    }
    __syncthreads();
    if (tid < NPROP) {
        int sidx = sel[tid];
        out[3*tid+0] = world[3*sidx+0];
        out[3*tid+1] = world[3*sidx+1];
        out[3*tid+2] = world[3*sidx+2];
        out[3*NPROP + tid] = 0.0f;                 // probs
        out[4*NPROP + 3*tid + 0] = scv[3*sidx+0];
        out[4*NPROP + 3*tid + 1] = scv[3*sidx+1];
        out[4*NPROP + 3*tid + 2] = scv[3*sidx+2];
    }
}

extern "C" void kernel_launch(void* const* d_in, const int* in_sizes, int n_in,
                              void* d_out, int out_size, void* d_ws, size_t ws_size,
                              hipStream_t stream) {
    const float* pc      = (const float*)d_in[0];
    const float* xyz     = (const float*)d_in[1];
    const float* scale   = (const float*)d_in[2];
    const float* prob    = (const float*)d_in[3];
    const float* corners = (const float*)d_in[4];
    const float* vp      = (const float*)d_in[5];
    int N = in_sizes[0] / 3;
    int M = in_sizes[5] / 3;
    int NV = N * NROT;
    int pblocks = (N + 255) / 256;

    const size_t G = (size_t)GXD * GYD * GZD;  // 8,286,208
    float* gobj    = (float*)d_ws;
    // ---- zeroed region (single memset): sumdist, bincnt, svcnt, hotcnt, packed, gsmall ----
    float* sumdist = gobj + G;                         // 1
    int*   bincnt  = (int*)(sumdist + 1);              // NBINS
    int*   svcnt   = bincnt + NBINS;                   // KSMP
    int*   hotcnt  = svcnt + KSMP;                     // 1 (also 8B-align pad)
    unsigned long long* packed = (unsigned long long*)(hotcnt + 1);  // CCLS u64
    float* gsmall  = (float*)(packed + CCLS);          // 3*HSLOTS
    size_t zero_bytes = (size_t)((char*)(gsmall + 3*HSLOTS) - (char*)sumdist);
    // ---- rest ----
    int*   binbase = (int*)(gsmall + 3*HSLOTS);
    int*   bincur  = binbase + NBINS;
    float* logits  = (float*)(bincur + NBINS);
    uint32_t* bth  = (uint32_t*)(logits + CCLS);
    int*   yidx    = (int*)(bth + CCLS);
    int*   samples = yidx + CCLS;
    int*   hkeys   = samples + KSMP;                   // memset 0xFF
    float* world   = (float*)(hkeys + HSLOTS);
    float* scv     = world + 3*KSMP;
    int*   keep    = (int*)(scv + 3*KSMP);
    uint2* svrec   = (uint2*)(((uintptr_t)(keep + KSMP) + 15) & ~(uintptr_t)15);
    int*   hotlist = (int*)(svrec + (size_t)KSMP * SVCAP);   // CCLS
    int*   hblk    = hotlist + CCLS;                         // pblocks*NBINS
    uint2* vrec    = (uint2*)(((uintptr_t)(hblk + (size_t)pblocks*NBINS) + 15) & ~(uintptr_t)15);
    size_t need = (size_t)((char*)(vrec + NV) - (char*)d_ws);
    if (ws_size < need) {
        fprintf(stderr, "kernel_launch: ws_size %zu < needed %zu\n", ws_size, need);
        return;
    }

    hipMemsetAsync(sumdist, 0, zero_bytes, stream);            // ~623 KB
    hipMemsetAsync(hkeys, 0xFF, HSLOTS*sizeof(int), stream);   // hkeys = -1

    // rotation table: f32 theta chain exactly as reference, cos/sin in double -> f32
    RotTab rt;
    const float twopi = (float)(2.0 * M_PI);
    for (int r = 0; r < NROT; ++r) {
        float th = (twopi * (float)r) / 36.0f;
        rt.c[r] = (float)cos((double)th);
        rt.s[r] = (float)sin((double)th);
    }

    // phase-A ballast split across the vote pipeline (sum == AUNITS = 9248)
    const int BAL1 = 2800, BAL2 = 2800, BAL3 = 1900, BAL4 = AUNITS - BAL1 - BAL2 - BAL3; // 1748

    k_count_b<<<pblocks + BAL1, 256, 0, stream>>>(pc, xyz, corners, N, rt, bincnt, hblk,
                                                  pblocks, 0, svcnt, svrec);
    k_prefix<<<1, 576, 0, stream>>>(bincnt, binbase, bincur);
    k_binwrite_b<<<pblocks + BAL2, 256, 0, stream>>>(pc, xyz, prob, corners, N, rt, bincur, hblk, vrec,
                                                     pblocks, BAL1, svcnt, svrec);
    k_accum<<<NBINS, 256, 0, stream>>>(binbase, bincnt, vrec, gobj, packed);
    k_colmax2_b<<<CBLK + BAL3, 256, 0, stream>>>(packed, logits, yidx, sumdist,
                                                 CBLK, BAL1 + BAL2, svcnt, svrec);
    k_hotthresh_b<<<CBLK + BAL4, 256, 0, stream>>>(logits, sumdist, bth, hotcnt, hotlist,
                                                   CBLK, BAL1 + BAL2 + BAL3, svcnt, svrec);
    k_phaseB<<<KSMP, 256, 0, stream>>>(bth, hotlist, hotcnt, svcnt, svrec);
    k_finalize<<<KSMP, 64, 0, stream>>>(logits, sumdist, svcnt, svrec, yidx, hkeys, samples);
    k_scale_scatter<<<pblocks, 256, 0, stream>>>(pc, xyz, scale, prob, corners, hkeys, gsmall, N, rt);
    k_post<<<KSMP, 256, 0, stream>>>(gobj, hkeys, gsmall, yidx, samples, corners, vp, M, world, scv, keep);
    k_select<<<1, 256, 0, stream>>>(world, scv, keep, (float*)d_out);
}

// Round 8
// 368.575 us; speedup vs baseline: 1.0897x; 1.0015x over previous
//
#include <hip/hip_runtime.h>
#include <math.h>
#include <stdio.h>
#include <stdint.h>

#define GXD 272
#define GYD 112
#define GZD 272
#define NROT 36
#define CCLS (GXD*GZD)     /* 73984 = 289*256 */
#define CBLK (CCLS/256)    /* 289 cell blocks */
#define KSMP 1024          /* NUM_PROPOSAL*OVERSAMPLE */
#define NPROP 256
#define HSLOTS 2048        /* sampled-cell hash table slots */
#define YH 56              /* y-half size */
#define NBINS (GXD*2)      /* 544: (x-slice, y-half) bins */
#define SLICE (GYD*GZD)    /* 30464 cells per x-slice */
#define SVCAP 96           /* survivor capacity per row (spec E~36) */
#define AROWS 32           /* rows per phase-A unit */
#define AUNITS (CBLK * (KSMP/AROWS))   /* 289*32 = 9248 ballast units */
#define TH_SPEC 0xFFE00000u  /* speculative bits threshold: p = 2^-11 */

struct RotTab { float c[NROT]; float s[NROT]; };

__device__ __forceinline__ uint32_t cell_hash(int flat) {
    return ((uint32_t)flat * 2654435761u) >> 21;  // top 11 bits -> 0..2047
}

// rotl via single v_alignbit_b32: alignbit(x,x,s) = rotr(x,s); rotl(x,r)=rotr(x,32-r)
#define ROTL_AB(x, r) __builtin_amdgcn_alignbit((x), (x), 32u - (r))

// ---------------- threefry2x32, key (0,42), counter (0,i), out = o0^o1 ----------------
// JAX partitionable random_bits semantics (verified bit-exact across rounds).
__device__ __forceinline__ uint32_t tf_bits(uint32_t i) {
    constexpr uint32_t K1  = 42u;
    constexpr uint32_t KS2 = 42u ^ 0x1BD11BDAu;
    uint32_t x0 = 0u, x1 = i + K1;                     // inj0 (k0 == 0)
#define TF_R(r)  { x0 += x1; x1 = ROTL_AB(x1, r); x1 ^= x0; }
#define TF_RI(r, I0, I1) { x1 += (I1); x0 = x0 + (I0) + x1; x1 = ROTL_AB(x1, r); x1 ^= x0; }
    TF_R(13) TF_R(15) TF_R(26) TF_R(6)
    TF_RI(17, K1,  KS2 + 1u)  TF_R(29) TF_R(16) TF_R(24)
    TF_RI(13, KS2, 2u)        TF_R(15) TF_R(26) TF_R(6)
    TF_RI(17, 0u,  K1 + 3u)   TF_R(29) TF_R(16) TF_R(24)
    TF_RI(13, K1,  KS2 + 4u)  TF_R(15) TF_R(26) TF_R(6)
#undef TF_R
#undef TF_RI
    return (x0 + KS2) ^ (x1 + 5u);                     // inj5 folded into output
}

__device__ __forceinline__ float uniform_from_bits(uint32_t b) {
    const float TINY = 1.1754943508222875e-38f; // np.finfo(float32).tiny
    float f = __uint_as_float((b >> 9) | 0x3f800000u) - 1.0f;
    float u = __fadd_rn(__fmul_rn(f, 1.0f), TINY);
    return fmaxf(TINY, u);
}

// gumbel = -log(-log(u)); f32 logs via double rounding (== correctly-rounded logf)
__device__ __forceinline__ float gumbel_from_u(float u) {
    float l1 = (float)log((double)u);
    float l2 = (float)log((double)(-l1));
    return -l2;
}

// ---------------- Phase A: speculative survivor recording (data-independent) ----------------
__device__ __forceinline__ void phaseA_unit(int unit, int* __restrict__ svcnt,
                                            uint2* __restrict__ svrec) {
    int cb = unit % CBLK;
    int rg = unit / CBLK;
    int c  = cb * 256 + threadIdx.x;
    int k0 = rg * AROWS;
    uint32_t i = (uint32_t)k0 * (uint32_t)CCLS + (uint32_t)c;
#pragma unroll 4
    for (int kk = 0; kk < AROWS; ++kk) {
        uint32_t bits = tf_bits(i);
        if (__builtin_expect(bits >= TH_SPEC, 0)) {
            int row = k0 + kk;
            int idx = atomicAdd(&svcnt[row], 1);
            if (idx < SVCAP) svrec[row * SVCAP + idx] = make_uint2((uint32_t)c, bits);
        }
        i += (uint32_t)CCLS;
    }
}

// ---- vote voxel helpers: MUST stay bit-identical across all passes ----
__device__ __forceinline__ bool vote_iy(float py, float oy, float c0y, int& iy) {
    float ty = __fadd_rn(py, oy);
    float vy = __fadd_rn(__fdiv_rn(__fsub_rn(ty, c0y), 0.03f), 0.5f);
    iy = (int)floorf(vy);
    return (iy >= 0 && iy < GYD);
}
__device__ __forceinline__ bool vote_xz(float px, float pz, float ox, float oz,
                                        float c, float s, float c0x, float c0z,
                                        int& ix, int& iz) {
    float rx = __fadd_rn(__fmul_rn(ox, c), __fmul_rn(oz, s));
    float rz = __fadd_rn(__fmul_rn(-ox, s), __fmul_rn(oz, c));
    float tx = __fadd_rn(px, rx);
    float tz = __fadd_rn(pz, rz);
    float vx = __fadd_rn(__fdiv_rn(__fsub_rn(tx, c0x), 0.03f), 0.5f);
    float vz = __fadd_rn(__fdiv_rn(__fsub_rn(tz, c0z), 0.03f), 0.5f);
    ix = (int)floorf(vx);
    iz = (int)floorf(vz);
    return (ix >= 0 && ix < GXD && iz >= 0 && iz < GZD);
}

// ---------------- K1a: count votes per bin + cache per-block hist  [+ phase-A ballast] ----------------
__global__ __launch_bounds__(256) void k_count_b(const float* __restrict__ pc, const float* __restrict__ xyz,
                          const float* __restrict__ corners, int N, RotTab rt,
                          int* __restrict__ bincnt, int* __restrict__ hblk,
                          int nOrig, int unitBase, int* __restrict__ svcnt, uint2* __restrict__ svrec) {
    if ((int)blockIdx.x >= nOrig) { phaseA_unit(unitBase + (int)blockIdx.x - nOrig, svcnt, svrec); return; }
    __shared__ int h[NBINS];
    int tid = threadIdx.x;
    for (int j = tid; j < NBINS; j += 256) h[j] = 0;
    __syncthreads();
    int i = blockIdx.x * 256 + tid;
    if (i < N) {
        float px = pc[3*i], py = pc[3*i+1], pz = pc[3*i+2];
        float ox = xyz[3*i], oy = xyz[3*i+1], oz = xyz[3*i+2];
        int iy;
        if (vote_iy(py, oy, corners[1], iy)) {
            int ybit = (iy >= YH) ? 1 : 0;
            float c0x = corners[0], c0z = corners[2];
            for (int r = 0; r < NROT; ++r) {
                int ix, iz;
                if (vote_xz(px, pz, ox, oz, rt.c[r], rt.s[r], c0x, c0z, ix, iz))
                    atomicAdd(&h[ix*2 + ybit], 1);
            }
        }
    }
    __syncthreads();
    int* hb = hblk + (size_t)blockIdx.x * NBINS;
    for (int j = tid; j < NBINS; j += 256) {
        int cnt = h[j];
        hb[j] = cnt;
        if (cnt) atomicAdd(&bincnt[j], cnt);
    }
}

// ---------------- K1b: parallel exclusive scan over 544 bins ----------------
__global__ __launch_bounds__(576) void k_prefix(const int* __restrict__ bincnt,
                         int* __restrict__ binbase, int* __restrict__ bincur) {
    __shared__ int sc[576];
    int tid = threadIdx.x;
    int v = (tid < NBINS) ? bincnt[tid] : 0;
    sc[tid] = v;
    __syncthreads();
    for (int off = 1; off < 576; off <<= 1) {
        int x = sc[tid];
        if (tid >= off) x += sc[tid - off];
        __syncthreads();
        sc[tid] = x;
        __syncthreads();
    }
    if (tid < NBINS) {
        int excl = sc[tid] - v;
        binbase[tid] = excl;
        bincur[tid] = excl;
    }
}

// ---------------- K1c: write packed vote records (i<<14 | rel)  [+ phase-A ballast] ----------------
// rel = (iy - ybit*YH)*GZD + iz < 15232 (14 bits); i < N <= 131072 (17 bits).
__global__ __launch_bounds__(256) void k_binwrite_b(const float* __restrict__ pc, const float* __restrict__ xyz,
                          const float* __restrict__ corners,
                          int N, RotTab rt, int* __restrict__ bincur,
                          const int* __restrict__ hblk, uint32_t* __restrict__ vrec,
                          int nOrig, int unitBase, int* __restrict__ svcnt, uint2* __restrict__ svrec) {
    if ((int)blockIdx.x >= nOrig) { phaseA_unit(unitBase + (int)blockIdx.x - nOrig, svcnt, svrec); return; }
    __shared__ int h[NBINS];      // local rank cursor
    __shared__ int bbase[NBINS];  // this block's base per bin
    int tid = threadIdx.x;
    const int* hb = hblk + (size_t)blockIdx.x * NBINS;
    for (int j = tid; j < NBINS; j += 256) {
        int cnt = hb[j];
        bbase[j] = cnt ? atomicAdd(&bincur[j], cnt) : 0;
        h[j] = 0;
    }
    __syncthreads();
    int i = blockIdx.x * 256 + tid;
    if (i < N) {
        float px = pc[3*i], py = pc[3*i+1], pz = pc[3*i+2];
        float ox = xyz[3*i], oy = xyz[3*i+1], oz = xyz[3*i+2];
        int iy;
        if (vote_iy(py, oy, corners[1], iy)) {
            int ybit = (iy >= YH) ? 1 : 0;
            int iyrel = iy - ybit*YH;
            float c0x = corners[0], c0z = corners[2];
            for (int r = 0; r < NROT; ++r) {
                int ix, iz;
                if (vote_xz(px, pz, ox, oz, rt.c[r], rt.s[r], c0x, c0z, ix, iz)) {
                    int bin = ix*2 + ybit;
                    int rank = atomicAdd(&h[bin], 1);
                    int slot = bbase[bin] + rank;
                    vrec[slot] = ((uint32_t)i << 14) | (uint32_t)(iyrel*GZD + iz);
                }
            }
        }
    }
}

// ---------------- K1d: per-bin LDS accumulate + packed column-max atomicMax ----------------
// gobj ELIMINATED: the only consumer (k_post) needs gobj at (x, argmax_y, z),
// which equals the column max m — recoverable from packed. 33MB of stores gone.
__global__ __launch_bounds__(256) void k_accum(const int* __restrict__ binbase,
                          const int* __restrict__ bincnt,
                          const uint32_t* __restrict__ vrec,
                          const float* __restrict__ prob,
                          unsigned long long* __restrict__ packed) {
    __shared__ float tile[YH*GZD];   // 56*272*4 = 60928 B
    int b = blockIdx.x;
    int x = b >> 1, yh = b & 1;
    int tid = threadIdx.x;
    for (int j = tid; j < YH*GZD; j += 256) tile[j] = 0.0f;
    __syncthreads();
    int lo = binbase[b], n = bincnt[b];
    for (int j = lo + tid; j < lo + n; j += 256) {
        uint32_t rec = vrec[j];
        atomicAdd(&tile[rec & 0x3FFFu], prob[rec >> 14]);
    }
    __syncthreads();
    int ybase = yh * YH;
    for (int z = tid; z < GZD; z += 256) {
        float m = tile[z];
        int mi = 0;
        for (int y = 1; y < YH; ++y) {
            float v = tile[y*GZD + z];
            if (v > m) { m = v; mi = y; }
        }
        unsigned long long key = ((unsigned long long)__float_as_uint(m) << 32)
                               | (unsigned long long)(uint32_t)(0x7F - (ybase + mi));
        atomicMax(&packed[x*GZD + z], key);
    }
}

// ---------------- K2: decode packed -> logits/yidx; sum(dist)  [+ phase-A ballast] ----------------
__global__ __launch_bounds__(256) void k_colmax2_b(const unsigned long long* __restrict__ packed,
                         float* __restrict__ logits, int* __restrict__ yidx,
                         float* __restrict__ sumdist,
                         int nOrig, int unitBase, int* __restrict__ svcnt, uint2* __restrict__ svrec) {
    if ((int)blockIdx.x >= nOrig) { phaseA_unit(unitBase + (int)blockIdx.x - nOrig, svcnt, svrec); return; }
    int c = blockIdx.x * 256 + threadIdx.x;
    unsigned long long key = packed[c];
    float m = __uint_as_float((uint32_t)(key >> 32));
    int mi = 0x7F - (int)(uint32_t)(key & 0xFFFFFFFFu);
    float d = __fsqrt_rn(__fadd_rn(m, 1e-7f));
    yidx[c] = mi;
    logits[c] = (float)log((double)__fadd_rn(d, 1e-30f));
    __shared__ float sred[256];
    int tid = threadIdx.x;
    sred[tid] = d; __syncthreads();
    for (int off = 128; off > 0; off >>= 1) {
        if (tid < off) sred[tid] += sred[tid+off];
        __syncthreads();
    }
    if (tid == 0) atomicAdd(sumdist, sred[0]);
}

// ---------------- K2b: bth + hot-cell list  [+ phase-A ballast] ----------------
__global__ __launch_bounds__(256) void k_hotthresh_b(const float* __restrict__ logits,
                                                     const float* __restrict__ sumdist,
                                                     uint32_t* __restrict__ bth,
                                                     int* __restrict__ hotcnt, int* __restrict__ hotlist,
                                                     int nOrig, int unitBase,
                                                     int* __restrict__ svcnt, uint2* __restrict__ svrec) {
    if ((int)blockIdx.x >= nOrig) { phaseA_unit(unitBase + (int)blockIdx.x - nOrig, svcnt, svrec); return; }
    int c = blockIdx.x * 256 + threadIdx.x;
    double B0 = log((double)*sumdist) - 3.0;
    double t = exp(-exp((double)logits[c] - (B0 - 0.05)));
    long long k_th = (long long)floor(t * 8388608.0) - 2;
    uint32_t b;
    if (k_th <= 0)              b = 0u;           // everything survives
    else if (k_th >= 8388608LL) b = 0xFFFFFFFFu;  // ~nothing survives (over-include, harmless)
    else                        b = (uint32_t)k_th << 9;
    bth[c] = b;
    if (b < TH_SPEC) {
        int idx = atomicAdd(hotcnt, 1);
        hotlist[idx] = c;
    }
}

// ---------------- K3b: phase-B exact retest of hot cells (disjoint band bits < TH_SPEC) ----------------
__global__ __launch_bounds__(256) void k_phaseB(const uint32_t* __restrict__ bth,
                                                const int* __restrict__ hotlist,
                                                const int* __restrict__ hotcnt,
                                                int* __restrict__ svcnt, uint2* __restrict__ svrec) {
    int k = blockIdx.x;
    int n = *hotcnt;
    uint32_t base = (uint32_t)k * (uint32_t)CCLS;
    for (int j = threadIdx.x; j < n; j += 256) {
        int c = hotlist[j];
        uint32_t bits = tf_bits(base + (uint32_t)c);
        if (bits >= bth[c] && bits < TH_SPEC) {
            int idx = atomicAdd(&svcnt[k], 1);
            if (idx < SVCAP) svrec[k * SVCAP + idx] = make_uint2((uint32_t)c, bits);
        }
    }
}

// ---------------- K3f: per-row argmax over records, exactness-checked + fused table insert ----------------
__global__ __launch_bounds__(64) void k_finalize(const float* __restrict__ logits,
                                                 const float* __restrict__ sumdist,
                                                 const int* __restrict__ svcnt,
                                                 const uint2* __restrict__ svrec,
                                                 const int* __restrict__ yidx,
                                                 int* __restrict__ hkeys,
                                                 int* __restrict__ samples) {
    int k = blockIdx.x;
    int tid = threadIdx.x;   // 64 threads = 1 wave
    int n = svcnt[k];
    float best = -INFINITY; int bc = 0x7fffffff;
    bool full = (n <= 0 || n > SVCAP);
    if (!full) {
        for (int j = tid; j < n; j += 64) {
            uint2 rec = svrec[k * SVCAP + j];
            int c = (int)rec.x;
            float v = __fadd_rn(gumbel_from_u(uniform_from_bits(rec.y)), logits[c]);
            if (v > best || (v == best && c < bc)) { best = v; bc = c; }
        }
        for (int off = 32; off > 0; off >>= 1) {
            float v2 = __shfl_xor(best, off);
            int   i2 = __shfl_xor(bc, off);
            if (v2 > best || (v2 == best && i2 < bc)) { best = v2; bc = i2; }
        }
        double B0 = log((double)*sumdist) - 3.0;
        if (!((double)best > B0 - 0.05)) full = true;   // winner might be unrecorded
    }
    if (full) {
        best = -INFINITY; bc = 0x7fffffff;
        uint32_t base = (uint32_t)k * (uint32_t)CCLS;
        for (int c = tid; c < CCLS; c += 64) {
            float v = __fadd_rn(gumbel_from_u(uniform_from_bits(tf_bits(base + (uint32_t)c))), logits[c]);
            if (v > best || (v == best && c < bc)) { best = v; bc = c; }
        }
        for (int off = 32; off > 0; off >>= 1) {
            float v2 = __shfl_xor(best, off);
            int   i2 = __shfl_xor(bc, off);
            if (v2 > best || (v2 == best && i2 < bc)) { best = v2; bc = i2; }
        }
    }
    if (tid == 0) {
        samples[k] = bc;
        int xi = bc / GZD, zi = bc % GZD;
        int yi = yidx[bc];
        int flat = (xi*GYD + yi)*GZD + zi;
        uint32_t h = cell_hash(flat);
        for (;;) {
            int prev = atomicCAS(&hkeys[h], -1, flat);
            if (prev == -1 || prev == flat) break;
            h = (h + 1) & (HSLOTS - 1);
        }
    }
}

// ---------------- K3c: replay votes (all 36 rots per thread), accumulate scale sums ----------------
__global__ __launch_bounds__(256) void k_scale_scatter(const float* __restrict__ pc, const float* __restrict__ xyz,
                          const float* __restrict__ scale, const float* __restrict__ prob,
                          const float* __restrict__ corners,
                          const int* __restrict__ hkeys, float* __restrict__ gsmall,
                          int N, RotTab rt) {
    __shared__ int lk[HSLOTS];
    for (int j = threadIdx.x; j < HSLOTS; j += 256) lk[j] = hkeys[j];
    __syncthreads();
    int i = blockIdx.x * 256 + threadIdx.x;
    if (i >= N) return;
    float px = pc[3*i], py = pc[3*i+1], pz = pc[3*i+2];
    float ox = xyz[3*i], oy = xyz[3*i+1], oz = xyz[3*i+2];
    int iy;
    if (!vote_iy(py, oy, corners[1], iy)) return;
    float c0x = corners[0], c0z = corners[2];
    int iyo = iy * GZD;
    float w0 = prob[i];
    float ws0 = __fmul_rn(w0, scale[3*i]);
    float ws1 = __fmul_rn(w0, scale[3*i+1]);
    float ws2 = __fmul_rn(w0, scale[3*i+2]);
    for (int r = 0; r < NROT; ++r) {
        int ix, iz;
        if (!vote_xz(px, pz, ox, oz, rt.c[r], rt.s[r], c0x, c0z, ix, iz)) continue;
        int flat = ix * SLICE + iyo + iz;
        uint32_t h = cell_hash(flat);
        int slot = -1;
        for (;;) {
            int key = lk[h];
            if (key == flat) { slot = (int)h; break; }
            if (key == -1) break;
            h = (h + 1) & (HSLOTS - 1);
        }
        if (slot < 0) continue;
        atomicAdd(&gsmall[3*slot+0], ws0);
        atomicAdd(&gsmall[3*slot+1], ws1);
        atomicAdd(&gsmall[3*slot+2], ws2);
    }
}

// ---------------- K4: one block per sample — world loc, scale, keep ----------------
// gobj replaced by packed: gobj[(xi, yidx[c], zi)] == column max m == packed[c]>>32.
__global__ __launch_bounds__(256) void k_post(const unsigned long long* __restrict__ packed,
                       const int* __restrict__ hkeys, const float* __restrict__ gsmall,
                       const int* __restrict__ yidx, const int* __restrict__ samples,
                       const float* __restrict__ corners, const float* __restrict__ vp, int M,
                       float* __restrict__ world, float* __restrict__ scv, int* __restrict__ keep) {
    int k = blockIdx.x;
    int tid = threadIdx.x;
    int s = samples[k];
    int xi = s / GZD, zi = s % GZD;
    int yi = yidx[s];
    float wx = __fadd_rn(__fmul_rn((float)xi, 0.03f), corners[0]);
    float wy = __fadd_rn(__fmul_rn((float)yi, 0.03f), corners[1]);
    float wz = __fadd_rn(__fmul_rn((float)zi, 0.03f), corners[2]);

    float dmin = INFINITY;
    for (int j = tid; j < M; j += 256) {
        float dx = __fsub_rn(wx, vp[3*j]);
        float dy = __fsub_rn(wy, vp[3*j+1]);
        float dz = __fsub_rn(wz, vp[3*j+2]);
        float sq = __fadd_rn(__fadd_rn(__fmul_rn(dx,dx), __fmul_rn(dy,dy)), __fmul_rn(dz,dz));
        dmin = fminf(dmin, __fsqrt_rn(sq));
    }
    __shared__ float sm[256];
    sm[tid] = dmin; __syncthreads();
    for (int off = 128; off > 0; off >>= 1) {
        if (tid < off) sm[tid] = fminf(sm[tid], sm[tid+off]);
        __syncthreads();
    }
    if (tid == 0) {
        world[3*k] = wx; world[3*k+1] = wy; world[3*k+2] = wz;
        int flat = (xi*GYD + yi)*GZD + zi;
        uint32_t h = cell_hash(flat);
        while (hkeys[h] != flat) h = (h + 1) & (HSLOTS - 1);  // guaranteed present
        float m = __uint_as_float((uint32_t)(packed[s] >> 32));
        float go = __fadd_rn(m, 1e-7f);
        scv[3*k+0] = __fdiv_rn(gsmall[3*h+0], go);
        scv[3*k+1] = __fdiv_rn(gsmall[3*h+1], go);
        scv[3*k+2] = __fdiv_rn(gsmall[3*h+2], go);
        keep[k] = (sm[0] < 0.3f) ? 1 : 0;
    }
}

// ---------------- K5: stable 0/1 selection via parallel prefix-sum ----------------
__global__ __launch_bounds__(256) void k_select(const float* __restrict__ world,
                                                const float* __restrict__ scv,
                                                const int* __restrict__ keep,
                                                float* __restrict__ out) {
    __shared__ int kp[KSMP];
    __shared__ int tsum[256];
    __shared__ int sel[NPROP];
    __shared__ int anyk;
    int tid = threadIdx.x;
    if (tid == 0) anyk = 0;
    __syncthreads();
    int a = 0;
    for (int j = tid; j < KSMP; j += 256) { int v = keep[j]; kp[j] = v; a |= v; }
    if (a) anyk = 1;           // benign race, all writers store 1
    __syncthreads();
    int any = anyk;
    int j0 = tid * 4;
    int k0v = any ? kp[j0]   : 1;
    int k1v = any ? kp[j0+1] : 1;
    int k2v = any ? kp[j0+2] : 1;
    int k3v = any ? kp[j0+3] : 1;
    int s0 = k0v, s1 = s0 + k1v, s2 = s1 + k2v, s3 = s2 + k3v;
    tsum[tid] = s3;
    __syncthreads();
    for (int off = 1; off < 256; off <<= 1) {
        int x = tsum[tid];
        if (tid >= off) x += tsum[tid - off];
        __syncthreads();
        tsum[tid] = x;
        __syncthreads();
    }
    int base = (tid > 0) ? tsum[tid-1] : 0;
    int nk = tsum[255];  // total kept
    int inc[4] = { base + s0, base + s1, base + s2, base + s3 };
    int kv[4]  = { k0v, k1v, k2v, k3v };
    for (int q = 0; q < 4; ++q) {
        int j = j0 + q;
        int slot = kv[q] ? (inc[q] - 1) : (nk + j - inc[q]);
        if (slot < NPROP) sel[slot] = j;
    }
    __syncthreads();
    if (tid < NPROP) {
        int sidx = sel[tid];
        out[3*tid+0] = world[3*sidx+0];
        out[3*tid+1] = world[3*sidx+1];
        out[3*tid+2] = world[3*sidx+2];
        out[3*NPROP + tid] = 0.0f;                 // probs
        out[4*NPROP + 3*tid + 0] = scv[3*sidx+0];
        out[4*NPROP + 3*tid + 1] = scv[3*sidx+1];
        out[4*NPROP + 3*tid + 2] = scv[3*sidx+2];
    }
}

extern "C" void kernel_launch(void* const* d_in, const int* in_sizes, int n_in,
                              void* d_out, int out_size, void* d_ws, size_t ws_size,
                              hipStream_t stream) {
    const float* pc      = (const float*)d_in[0];
    const float* xyz     = (const float*)d_in[1];
    const float* scale   = (const float*)d_in[2];
    const float* prob    = (const float*)d_in[3];
    const float* corners = (const float*)d_in[4];
    const float* vp      = (const float*)d_in[5];
    int N = in_sizes[0] / 3;
    int M = in_sizes[5] / 3;
    int NV = N * NROT;
    int pblocks = (N + 255) / 256;
    if (N > (1 << 17)) {   // vrec packing requires i < 2^17 (ref N = 100000)
        fprintf(stderr, "kernel_launch: N %d exceeds packing limit\n", N);
        return;
    }

    // ---- zeroed region (single memset): sumdist, bincnt, svcnt, hotcnt, packed, gsmall ----
    float* sumdist = (float*)d_ws;                     // 1
    int*   bincnt  = (int*)(sumdist + 1);              // NBINS
    int*   svcnt   = bincnt + NBINS;                   // KSMP
    int*   hotcnt  = svcnt + KSMP;                     // 1 (also 8B-align pad)
    unsigned long long* packed = (unsigned long long*)(hotcnt + 1);  // CCLS u64
    float* gsmall  = (float*)(packed + CCLS);          // 3*HSLOTS
    size_t zero_bytes = (size_t)((char*)(gsmall + 3*HSLOTS) - (char*)sumdist);
    // ---- rest ----
    int*   binbase = (int*)(gsmall + 3*HSLOTS);
    int*   bincur  = binbase + NBINS;
    float* logits  = (float*)(bincur + NBINS);
    uint32_t* bth  = (uint32_t*)(logits + CCLS);
    int*   yidx    = (int*)(bth + CCLS);
    int*   samples = yidx + CCLS;
    int*   hkeys   = samples + KSMP;                   // memset 0xFF
    float* world   = (float*)(hkeys + HSLOTS);
    float* scv     = world + 3*KSMP;
    int*   keep    = (int*)(scv + 3*KSMP);
    uint2* svrec   = (uint2*)(((uintptr_t)(keep + KSMP) + 15) & ~(uintptr_t)15);
    int*   hotlist = (int*)(svrec + (size_t)KSMP * SVCAP);   // CCLS
    int*   hblk    = hotlist + CCLS;                         // pblocks*NBINS
    uint32_t* vrec = (uint32_t*)(((uintptr_t)(hblk + (size_t)pblocks*NBINS) + 15) & ~(uintptr_t)15);
    size_t need = (size_t)((char*)(vrec + NV) - (char*)d_ws);
    if (ws_size < need) {
        fprintf(stderr, "kernel_launch: ws_size %zu < needed %zu\n", ws_size, need);
        return;
    }

    hipMemsetAsync(sumdist, 0, zero_bytes, stream);            // ~623 KB
    hipMemsetAsync(hkeys, 0xFF, HSLOTS*sizeof(int), stream);   // hkeys = -1

    // rotation table: f32 theta chain exactly as reference, cos/sin in double -> f32
    RotTab rt;
    const float twopi = (float)(2.0 * M_PI);
    for (int r = 0; r < NROT; ++r) {
        float th = (twopi * (float)r) / 36.0f;
        rt.c[r] = (float)cos((double)th);
        rt.s[r] = (float)sin((double)th);
    }

    // phase-A ballast split across the vote pipeline (sum == AUNITS = 9248)
    const int BAL1 = 2800, BAL2 = 2800, BAL3 = 1900, BAL4 = AUNITS - BAL1 - BAL2 - BAL3; // 1748

    k_count_b<<<pblocks + BAL1, 256, 0, stream>>>(pc, xyz, corners, N, rt, bincnt, hblk,
                                                  pblocks, 0, svcnt, svrec);
    k_prefix<<<1, 576, 0, stream>>>(bincnt, binbase, bincur);
    k_binwrite_b<<<pblocks + BAL2, 256, 0, stream>>>(pc, xyz, corners, N, rt, bincur, hblk, vrec,
                                                     pblocks, BAL1, svcnt, svrec);
    k_accum<<<NBINS, 256, 0, stream>>>(binbase, bincnt, vrec, prob, packed);
    k_colmax2_b<<<CBLK + BAL3, 256, 0, stream>>>(packed, logits, yidx, sumdist,
                                                 CBLK, BAL1 + BAL2, svcnt, svrec);
    k_hotthresh_b<<<CBLK + BAL4, 256, 0, stream>>>(logits, sumdist, bth, hotcnt, hotlist,
                                                   CBLK, BAL1 + BAL2 + BAL3, svcnt, svrec);
    k_phaseB<<<KSMP, 256, 0, stream>>>(bth, hotlist, hotcnt, svcnt, svrec);
    k_finalize<<<KSMP, 64, 0, stream>>>(logits, sumdist, svcnt, svrec, yidx, hkeys, samples);
    k_scale_scatter<<<pblocks, 256, 0, stream>>>(pc, xyz, scale, prob, corners, hkeys, gsmall, N, rt);
    k_post<<<KSMP, 256, 0, stream>>>(packed, hkeys, gsmall, yidx, samples, corners, vp, M, world, scv, keep);
    k_select<<<1, 256, 0, stream>>>(world, scv, keep, (float*)d_out);
}